// Round 9
// baseline (563.102 us; speedup 1.0000x reference)
//
#include <hip/hip_runtime.h>
#include <hip/hip_bf16.h>

typedef unsigned short ushort_t;
typedef unsigned int uint_t;
typedef short short8 __attribute__((ext_vector_type(8)));
typedef float floatx4 __attribute__((ext_vector_type(4)));

// ---------- bf16 helpers (raw ushort storage) ----------
__device__ inline float b2f(ushort_t u){
    uint_t v = ((uint_t)u) << 16;
    return __uint_as_float(v);
}
__device__ inline ushort_t f2b(float f){
    uint_t v = __float_as_uint(f);
    uint_t r = (v + 0x7FFFu + ((v >> 16) & 1u)) >> 16;  // RNE
    return (ushort_t)r;
}
__device__ inline void unpack8(uint4 u, float* f){
    uint_t w[4] = {u.x, u.y, u.z, u.w};
    #pragma unroll
    for (int i = 0; i < 4; ++i){
        f[2*i]   = __uint_as_float(w[i] << 16);
        f[2*i+1] = __uint_as_float(w[i] & 0xFFFF0000u);
    }
}
__device__ inline uint4 pack8(const float* f){
    uint4 o;
    uint_t w[4];
    #pragma unroll
    for (int i = 0; i < 4; ++i)
        w[i] = (uint_t)f2b(f[2*i]) | ((uint_t)f2b(f[2*i+1]) << 16);
    o.x = w[0]; o.y = w[1]; o.z = w[2]; o.w = w[3];
    return o;
}
__device__ inline ushort4 cvt4(float4 v){
    ushort4 o;
    o.x = f2b(v.x); o.y = f2b(v.y); o.z = f2b(v.z); o.w = f2b(v.w);
    return o;
}
__device__ inline float hswish(float y){
    return y * fminf(fmaxf(y + 3.f, 0.f), 6.f) * (1.f/6.f);
}

// ---------- constants ----------
#define MROWS 6272
#define CDIM  768
#define HID   3072
#define QKV3  2304

// swin window->spatial row map (with +3 roll): ri (window layout) -> dest row (b*196+p)
__device__ inline int scatter_row(int ri){
    int w  = ri / 49, t = ri % 49;
    int b  = w >> 2,  wi = w & 3;
    int wy = wi >> 1, wx = wi & 1;
    int ty = t / 7,   tx = t % 7;
    int yd = (wy*7 + ty + 3) % 14;
    int xd = (wx*7 + tx + 3) % 14;
    return b*196 + yd*14 + xd;
}

// bn scale/shift from raw sums (folded bn_finalize)
__device__ inline void bn_coef(const float* __restrict__ sums, int Cch,
                               const float* __restrict__ g, const float* __restrict__ b,
                               int c, float& sc, float& sh){
    float mean = sums[c] * (1.f/6272.f);
    float var  = sums[Cch + c] * (1.f/6272.f) - mean*mean;
    float s = g[c] * rsqrtf(var + 1e-5f);
    sc = s;
    sh = b[c] - mean*s;
}

// ---------- fp32 -> bf16 cast (weights) ----------
__global__ __launch_bounds__(256) void cvt_f2b(const float4* __restrict__ in,
                                               ushort4* __restrict__ out, int n4){
    int i = blockIdx.x * 256 + threadIdx.x;
    if (i < n4) out[i] = cvt4(in[i]);
}

// ---------- dw weight transpose: [3072][9] -> [9][3072] ----------
__global__ __launch_bounds__(256) void dw_transpose(const float* __restrict__ w,
                                                    float* __restrict__ wT){
    int i = blockIdx.x*256 + threadIdx.x;
    if (i < HID*9){ int c = i/9, k = i%9; wT[k*HID + c] = w[i]; }
}

// ---------- window gather: x fp32 (B,197,C) -> win bf16 (128*49, C), shifted ----------
__global__ __launch_bounds__(256) void gather_win(const float4* __restrict__ x,
                                                  ushort4* __restrict__ win){
    int idx = blockIdx.x * 256 + threadIdx.x;
    if (idx >= MROWS * 192) return;
    int r  = idx / 192, c4 = idx % 192;
    int w  = r / 49,  t  = r % 49;
    int b  = w >> 2,  wi = w & 3;
    int wy = wi >> 1, wx = wi & 1;
    int ty = t / 7,   tx = t % 7;
    int ys = (wy*7 + ty + 3) % 14;                       // roll(-3)
    int xs = (wx*7 + tx + 3) % 14;
    win[idx] = cvt4(x[(size_t)b*197*192 + (size_t)(1 + ys*14 + xs)*192 + c4]);
}

// ---------- MFMA GEMM 128x128 tile (qkv / pw1) ----------
__global__ __launch_bounds__(256) void gemm_bt(const ushort_t* __restrict__ A,
                                               const ushort_t* __restrict__ B,
                                               ushort_t* __restrict__ Cb,
                                               float* __restrict__ Cf,
                                               int M, int N, int K,
                                               const float* __restrict__ bias,
                                               float* __restrict__ stats,
                                               int scat){
    const int nx   = gridDim.x;
    int flat = blockIdx.y * nx + blockIdx.x;
    int xcd  = flat & 7;
    int k    = flat >> 3;
    int by   = xcd + 8 * (k / nx);
    int bx   = k % nx;
    if (by * 128 >= M) return;

    __shared__ __align__(16) ushort_t As[2][128*32];
    __shared__ __align__(16) ushort_t Bs[2][128*32];
    const int tid  = threadIdx.x;
    const int lane = tid & 63;
    const int wid  = tid >> 6;
    const int m0 = by * 128;
    const int n0 = bx * 128;
    const int wm = (wid >> 1) * 64;
    const int wn = (wid & 1) * 64;

    const int srow = (lane >> 2);
    const int scol = (((lane & 3) ^ ((lane >> 3) & 3)) * 8);

    floatx4 acc[4][4] = {};

    auto stage = [&](int buf, int k0){
        #pragma unroll
        for (int j = 0; j < 2; ++j){
            int ch  = wid*2 + j;
            const ushort_t* gA = A + (size_t)(m0 + ch*16 + srow)*K + k0 + scol;
            const ushort_t* gB = B + (size_t)(n0 + ch*16 + srow)*K + k0 + scol;
            __builtin_amdgcn_global_load_lds(
                (const __attribute__((address_space(1))) void*)gA,
                (__attribute__((address_space(3))) void*)(&As[buf][ch*512 + lane*8]), 16, 0, 0);
            __builtin_amdgcn_global_load_lds(
                (const __attribute__((address_space(1))) void*)gB,
                (__attribute__((address_space(3))) void*)(&Bs[buf][ch*512 + lane*8]), 16, 0, 0);
        }
    };

    const int NK = K >> 5;
    stage(0, 0);

    const int fr   = lane & 15;
    const int quad = lane >> 4;
    const int cosw = (quad ^ ((fr >> 1) & 3)) * 8;
    int cur = 0;
    for (int it = 0; it < NK; ++it){
        __builtin_amdgcn_sched_barrier(0);
        __builtin_amdgcn_s_barrier();
        if (it + 1 < NK){
            stage(cur ^ 1, (it + 1) << 5);
            asm volatile("s_waitcnt vmcnt(4)" ::: "memory");
        } else {
            asm volatile("s_waitcnt vmcnt(0)" ::: "memory");
        }
        __builtin_amdgcn_s_barrier();
        __builtin_amdgcn_sched_barrier(0);

        short8 af[4], bfr[4];
        #pragma unroll
        for (int i = 0; i < 4; ++i){
            af[i]  = *(const short8*)(&As[cur][(wm + i*16 + fr)*32 + cosw]);
            bfr[i] = *(const short8*)(&Bs[cur][(wn + i*16 + fr)*32 + cosw]);
        }
        #pragma unroll
        for (int i = 0; i < 4; ++i)
            #pragma unroll
            for (int j = 0; j < 4; ++j)
                acc[i][j] = __builtin_amdgcn_mfma_f32_16x16x32_bf16(af[i], bfr[j], acc[i][j], 0, 0, 0);
        cur ^= 1;
    }

    if (!scat && Cb){
        __syncthreads();
        ushort_t* Cspace = (wid < 2) ? &As[0][0] : &Bs[0][0];
        #pragma unroll
        for (int i = 0; i < 4; ++i){
            #pragma unroll
            for (int j = 0; j < 4; ++j){
                int col = wn + j*16 + fr;
                float bv = bias ? bias[n0 + col] : 0.f;
                #pragma unroll
                for (int r = 0; r < 4; ++r)
                    Cspace[(i*16 + quad*4 + r)*128 + (col ^ (quad << 4))] =
                        f2b(acc[i][j][r] + bv);
            }
        }
        __syncthreads();
        #pragma unroll
        for (int q = 0; q < 8; ++q){
            int fl  = q*256 + tid;
            int row = fl >> 4, u4c = fl & 15;
            const ushort_t* srcRow = (row < 64) ? (&As[0][0] + row*128)
                                                : (&Bs[0][0] + (row - 64)*128);
            int g = (row >> 2) & 3;
            *(uint4*)(Cb + (size_t)(m0 + row)*N + n0 + u4c*8) =
                *(const uint4*)(srcRow + ((u4c*8) ^ (g << 4)));
        }
    } else {
        #pragma unroll
        for (int i = 0; i < 4; ++i){
            int grow = m0 + wm + i*16 + quad*4;
            #pragma unroll
            for (int j = 0; j < 4; ++j){
                int gcol = n0 + wn + j*16 + fr;
                float bv = bias ? bias[gcol] : 0.f;
                if (scat){
                    #pragma unroll
                    for (int r = 0; r < 4; ++r){
                        float v = acc[i][j][r] + bv;
                        size_t off = (size_t)scatter_row(grow + r)*N + gcol;
                        if (Cf) Cf[off] = v;
                        Cb[off] = f2b(v);
                    }
                } else {
                    #pragma unroll
                    for (int r = 0; r < 4; ++r)
                        Cf[(size_t)(grow + r)*N + gcol] = acc[i][j][r] + bv;
                }
            }
        }
    }

    if (stats){
        #pragma unroll
        for (int j = 0; j < 4; ++j){
            int gcol = n0 + wn + j*16 + fr;
            float bv = bias ? bias[gcol] : 0.f;
            float sv = 0.f, sq = 0.f;
            #pragma unroll
            for (int i = 0; i < 4; ++i)
                #pragma unroll
                for (int r = 0; r < 4; ++r){
                    float v = acc[i][j][r] + bv;
                    sv += v; sq += v*v;
                }
            sv += __shfl_xor(sv, 16, 64);  sq += __shfl_xor(sq, 16, 64);
            sv += __shfl_xor(sv, 32, 64);  sq += __shfl_xor(sq, 32, 64);
            if (lane < 16){
                atomicAdd(&stats[gcol], sv);
                atomicAdd(&stats[N + gcol], sq);
            }
        }
    }
}

// ---------- MFMA GEMM 128x64 tile (proj: scat path) ----------
__global__ __launch_bounds__(256) void gemm_bt64(const ushort_t* __restrict__ A,
                                                 const ushort_t* __restrict__ B,
                                                 ushort_t* __restrict__ Cb,
                                                 float* __restrict__ Cf,
                                                 int M, int N, int K,
                                                 const float* __restrict__ bias,
                                                 float* __restrict__ stats,
                                                 int scat){
    const int nx   = gridDim.x;
    int flat = blockIdx.y * nx + blockIdx.x;
    int xcd  = flat & 7;
    int k    = flat >> 3;
    int by   = xcd + 8 * (k / nx);
    int bx   = k % nx;
    if (by * 128 >= M) return;

    __shared__ __align__(16) ushort_t As[2][128*32];
    __shared__ __align__(16) ushort_t Bs[2][64*32];
    const int tid  = threadIdx.x;
    const int lane = tid & 63;
    const int wid  = tid >> 6;
    const int m0 = by * 128;
    const int n0 = bx * 64;
    const int wm = (wid >> 1) * 64;
    const int wn = (wid & 1) * 32;

    const int srow = (lane >> 2);
    const int scol = (((lane & 3) ^ ((lane >> 3) & 3)) * 8);

    floatx4 acc[4][2] = {};

    auto stage = [&](int buf, int k0){
        #pragma unroll
        for (int j = 0; j < 2; ++j){
            int ch = wid*2 + j;
            const ushort_t* gA = A + (size_t)(m0 + ch*16 + srow)*K + k0 + scol;
            __builtin_amdgcn_global_load_lds(
                (const __attribute__((address_space(1))) void*)gA,
                (__attribute__((address_space(3))) void*)(&As[buf][ch*512 + lane*8]), 16, 0, 0);
        }
        const ushort_t* gB = B + (size_t)(n0 + wid*16 + srow)*K + k0 + scol;
        __builtin_amdgcn_global_load_lds(
            (const __attribute__((address_space(1))) void*)gB,
            (__attribute__((address_space(3))) void*)(&Bs[buf][wid*512 + lane*8]), 16, 0, 0);
    };

    const int NK = K >> 5;
    stage(0, 0);

    const int fr   = lane & 15;
    const int quad = lane >> 4;
    const int cosw = (quad ^ ((fr >> 1) & 3)) * 8;
    int cur = 0;
    for (int it = 0; it < NK; ++it){
        __builtin_amdgcn_sched_barrier(0);
        __builtin_amdgcn_s_barrier();
        if (it + 1 < NK){
            stage(cur ^ 1, (it + 1) << 5);
            asm volatile("s_waitcnt vmcnt(3)" ::: "memory");
        } else {
            asm volatile("s_waitcnt vmcnt(0)" ::: "memory");
        }
        __builtin_amdgcn_s_barrier();
        __builtin_amdgcn_sched_barrier(0);

        short8 af[4], bfr[2];
        #pragma unroll
        for (int i = 0; i < 4; ++i)
            af[i]  = *(const short8*)(&As[cur][(wm + i*16 + fr)*32 + cosw]);
        #pragma unroll
        for (int j = 0; j < 2; ++j)
            bfr[j] = *(const short8*)(&Bs[cur][(wn + j*16 + fr)*32 + cosw]);
        #pragma unroll
        for (int i = 0; i < 4; ++i)
            #pragma unroll
            for (int j = 0; j < 2; ++j)
                acc[i][j] = __builtin_amdgcn_mfma_f32_16x16x32_bf16(af[i], bfr[j], acc[i][j], 0, 0, 0);
        cur ^= 1;
    }

    if (!scat && Cb){
        __syncthreads();
        ushort_t* Cst = &As[0][0];
        #pragma unroll
        for (int i = 0; i < 4; ++i){
            #pragma unroll
            for (int j = 0; j < 2; ++j){
                int col = wn + j*16 + fr;
                float bv = bias ? bias[n0 + col] : 0.f;
                #pragma unroll
                for (int r = 0; r < 4; ++r)
                    Cst[(wm + i*16 + quad*4 + r)*64 + (col ^ (quad << 4))] =
                        f2b(acc[i][j][r] + bv);
            }
        }
        __syncthreads();
        #pragma unroll
        for (int q = 0; q < 4; ++q){
            int fl  = q*256 + tid;
            int row = fl >> 3, u4c = fl & 7;
            int g = (row >> 2) & 3;
            *(uint4*)(Cb + (size_t)(m0 + row)*N + n0 + u4c*8) =
                *(const uint4*)(Cst + row*64 + ((u4c*8) ^ (g << 4)));
        }
    } else {
        #pragma unroll
        for (int i = 0; i < 4; ++i){
            int grow = m0 + wm + i*16 + quad*4;
            #pragma unroll
            for (int j = 0; j < 2; ++j){
                int gcol = n0 + wn + j*16 + fr;
                float bv = bias ? bias[gcol] : 0.f;
                if (scat){
                    #pragma unroll
                    for (int r = 0; r < 4; ++r){
                        float v = acc[i][j][r] + bv;
                        size_t off = (size_t)scatter_row(grow + r)*N + gcol;
                        if (Cf) Cf[off] = v;
                        Cb[off] = f2b(v);
                    }
                } else {
                    #pragma unroll
                    for (int r = 0; r < 4; ++r)
                        Cf[(size_t)(grow + r)*N + gcol] = acc[i][j][r] + bv;
                }
            }
        }
    }

    if (stats){
        #pragma unroll
        for (int j = 0; j < 2; ++j){
            int gcol = n0 + wn + j*16 + fr;
            float bv = bias ? bias[gcol] : 0.f;
            float sv = 0.f, sq = 0.f;
            #pragma unroll
            for (int i = 0; i < 4; ++i)
                #pragma unroll
                for (int r = 0; r < 4; ++r){
                    float v = acc[i][j][r] + bv;
                    sv += v; sq += v*v;
                }
            sv += __shfl_xor(sv, 16, 64);  sq += __shfl_xor(sq, 16, 64);
            sv += __shfl_xor(sv, 32, 64);  sq += __shfl_xor(sq, 32, 64);
            if (lane < 16){
                atomicAdd(&stats[gcol], sv);
                atomicAdd(&stats[N + gcol], sq);
            }
        }
    }
}

// ---------- split-K=2 GEMM 128x64 (pw2): atomicAdd fp32 partial ----------
__global__ __launch_bounds__(256) void gemm_bt64_sk(const ushort_t* __restrict__ A,
                                                    const ushort_t* __restrict__ B,
                                                    float* __restrict__ P,
                                                    int M, int N, int K){
    const int nx   = gridDim.x;
    int flat = blockIdx.y * nx + blockIdx.x;
    int xcd  = flat & 7;
    int k    = flat >> 3;
    int by   = xcd + 8 * (k / nx);
    int bx   = k % nx;
    if (by * 128 >= M) return;
    const int kbeg = blockIdx.z * (K >> 1);

    __shared__ __align__(16) ushort_t As[2][128*32];
    __shared__ __align__(16) ushort_t Bs[2][64*32];
    const int tid  = threadIdx.x;
    const int lane = tid & 63;
    const int wid  = tid >> 6;
    const int m0 = by * 128;
    const int n0 = bx * 64;
    const int wm = (wid >> 1) * 64;
    const int wn = (wid & 1) * 32;

    const int srow = (lane >> 2);
    const int scol = (((lane & 3) ^ ((lane >> 3) & 3)) * 8);

    floatx4 acc[4][2] = {};

    auto stage = [&](int buf, int k0){
        #pragma unroll
        for (int j = 0; j < 2; ++j){
            int ch = wid*2 + j;
            const ushort_t* gA = A + (size_t)(m0 + ch*16 + srow)*K + kbeg + k0 + scol;
            __builtin_amdgcn_global_load_lds(
                (const __attribute__((address_space(1))) void*)gA,
                (__attribute__((address_space(3))) void*)(&As[buf][ch*512 + lane*8]), 16, 0, 0);
        }
        const ushort_t* gB = B + (size_t)(n0 + wid*16 + srow)*K + kbeg + k0 + scol;
        __builtin_amdgcn_global_load_lds(
            (const __attribute__((address_space(1))) void*)gB,
            (__attribute__((address_space(3))) void*)(&Bs[buf][wid*512 + lane*8]), 16, 0, 0);
    };

    const int NK = K >> 6;          // half-K / 32
    stage(0, 0);

    const int fr   = lane & 15;
    const int quad = lane >> 4;
    const int cosw = (quad ^ ((fr >> 1) & 3)) * 8;
    int cur = 0;
    for (int it = 0; it < NK; ++it){
        __builtin_amdgcn_sched_barrier(0);
        __builtin_amdgcn_s_barrier();
        if (it + 1 < NK){
            stage(cur ^ 1, (it + 1) << 5);
            asm volatile("s_waitcnt vmcnt(3)" ::: "memory");
        } else {
            asm volatile("s_waitcnt vmcnt(0)" ::: "memory");
        }
        __builtin_amdgcn_s_barrier();
        __builtin_amdgcn_sched_barrier(0);

        short8 af[4], bfr[2];
        #pragma unroll
        for (int i = 0; i < 4; ++i)
            af[i]  = *(const short8*)(&As[cur][(wm + i*16 + fr)*32 + cosw]);
        #pragma unroll
        for (int j = 0; j < 2; ++j)
            bfr[j] = *(const short8*)(&Bs[cur][(wn + j*16 + fr)*32 + cosw]);
        #pragma unroll
        for (int i = 0; i < 4; ++i)
            #pragma unroll
            for (int j = 0; j < 2; ++j)
                acc[i][j] = __builtin_amdgcn_mfma_f32_16x16x32_bf16(af[i], bfr[j], acc[i][j], 0, 0, 0);
        cur ^= 1;
    }

    #pragma unroll
    for (int i = 0; i < 4; ++i){
        int grow = m0 + wm + i*16 + quad*4;
        #pragma unroll
        for (int j = 0; j < 2; ++j){
            int gcol = n0 + wn + j*16 + fr;
            #pragma unroll
            for (int r = 0; r < 4; ++r)
                atomicAdd(&P[(size_t)(grow + r)*N + gcol], acc[i][j][r]);
        }
    }
}

// ---------- combine: fp32 partial -> bf16 + bn3 raw stats ----------
__global__ __launch_bounds__(256) void combine_k(const float* __restrict__ p,
                                                 ushort_t* __restrict__ outb,
                                                 float* __restrict__ sums){
    const int cgl = threadIdx.x & 31;
    const int rp  = threadIdx.x >> 5;
    const int cg  = blockIdx.x*32 + cgl;          // uint4 column, [0,96)
    const int r0  = blockIdx.y*224;
    float s[8] = {}, q[8] = {};
    for (int r = r0 + rp; r < r0 + 224; r += 8){
        const float4* pr = (const float4*)(p + (size_t)r*CDIM + cg*8);
        float4 a = pr[0], b = pr[1];
        float f[8] = {a.x,a.y,a.z,a.w,b.x,b.y,b.z,b.w};
        #pragma unroll
        for (int e = 0; e < 8; ++e){ s[e] += f[e]; q[e] += f[e]*f[e]; }
        ((uint4*)outb)[(size_t)r*96 + cg] = pack8(f);
    }
    #pragma unroll
    for (int e = 0; e < 8; ++e){
        s[e] += __shfl_xor(s[e], 32, 64);
        q[e] += __shfl_xor(q[e], 32, 64);
    }
    __shared__ float red[4][32][17];
    const int wv = threadIdx.x >> 6;
    if ((threadIdx.x & 32) == 0){
        #pragma unroll
        for (int e = 0; e < 8; ++e){
            red[wv][cgl][e]   = s[e];
            red[wv][cgl][8+e] = q[e];
        }
    }
    __syncthreads();
    #pragma unroll
    for (int k = 0; k < 2; ++k){
        int o = threadIdx.x*2 + k;          // [0,512)
        int cgo = o >> 4, e = o & 15;
        float v = red[0][cgo][e] + red[1][cgo][e] + red[2][cgo][e] + red[3][cgo][e];
        int c = blockIdx.x*256 + cgo*8 + (e & 7);
        atomicAdd(&sums[(e < 8 ? 0 : CDIM) + c], v);
    }
}

// ---------- bias+mask table ----------
__global__ __launch_bounds__(256) void bm_precompute(const float* __restrict__ rpb,
                                                     float* __restrict__ bm){
    int idx = blockIdx.x*256 + threadIdx.x;
    if (idx >= 12*4*64*64) return;
    int ki = idx & 63, qi = (idx >> 6) & 63, wi = (idx >> 12) & 3, h = idx >> 14;
    float v = -1e30f;
    if (qi < 49 && ki < 49){
        int qy = qi/7, qx = qi%7, ky = ki/7, kx = ki%7;
        int ridx = (qy - ky + 6)*13 + (qx - kx + 6);
        v = rpb[ridx*12 + h];
        int wy = wi >> 1, wx = wi & 1;
        int gqy = wy*7 + qy, gqx = wx*7 + qx, gky = wy*7 + ky, gkx = wx*7 + kx;
        int cq = ((gqy < 7) ? 0 : (gqy < 11 ? 1 : 2))*3 + ((gqx < 7) ? 0 : (gqx < 11 ? 1 : 2));
        int ck = ((gky < 7) ? 0 : (gky < 11 ? 1 : 2))*3 + ((gkx < 7) ? 0 : (gkx < 11 ? 1 : 2));
        if (cq != ck) v -= 100.f;
    }
    bm[idx] = v;
}

// ---------- MFMA attention ----------
__global__ __launch_bounds__(256) void attn_mfma(const ushort_t* __restrict__ qkv,
                                                 ushort_t* __restrict__ outp,
                                                 const float* __restrict__ bm){
    __shared__ __align__(16) ushort_t Ps[64*72];
    __shared__ __align__(16) ushort_t VT[64*72];
    const int tid = threadIdx.x, lane = tid & 63, wid = tid >> 6;
    const int h = blockIdx.x, w = blockIdx.y, wi = w & 3;
    const int fr = lane & 15, quad = lane >> 4, co = quad*8;

    for (int idx = tid; idx < 64*8; idx += 256){
        int k = idx >> 3, ng = idx & 7;
        uint4 u = {0u, 0u, 0u, 0u};
        if (k < 49) u = *(const uint4*)(qkv + (size_t)(w*49 + k)*QKV3 + 1536 + h*64 + ng*8);
        const ushort_t* vp = (const ushort_t*)&u;
        #pragma unroll
        for (int e = 0; e < 8; ++e) VT[(ng*8 + e)*72 + k] = vp[e];
    }
    __syncthreads();

    floatx4 accs[4] = {};
    const ushort_t* qbase = qkv + (size_t)(w*49 + wid*16 + fr)*QKV3 + h*64;
    #pragma unroll
    for (int k0 = 0; k0 < 64; k0 += 32){
        short8 af = *(const short8*)(qbase + k0 + co);
        #pragma unroll
        for (int j = 0; j < 4; ++j){
            const ushort_t* kbase = qkv + (size_t)(w*49 + j*16 + fr)*QKV3 + 768 + h*64;
            short8 bf = *(const short8*)(kbase + k0 + co);
            accs[j] = __builtin_amdgcn_mfma_f32_16x16x32_bf16(af, bf, accs[j], 0, 0, 0);
        }
    }

    const float* bmh = bm + (size_t)((h*4 + wi)*64 + wid*16)*64;
    #pragma unroll
    for (int r = 0; r < 4; ++r){
        int lrow = quad*4 + r;
        float m = -3e38f;
        #pragma unroll
        for (int j = 0; j < 4; ++j){
            float a = accs[j][r]*0.125f + bmh[lrow*64 + j*16 + fr];
            accs[j][r] = a;
            m = fmaxf(m, a);
        }
        #pragma unroll
        for (int off = 1; off < 16; off <<= 1) m = fmaxf(m, __shfl_xor(m, off, 64));
        float s = 0.f;
        #pragma unroll
        for (int j = 0; j < 4; ++j){
            float e = __expf(accs[j][r] - m);
            accs[j][r] = e; s += e;
        }
        #pragma unroll
        for (int off = 1; off < 16; off <<= 1) s += __shfl_xor(s, off, 64);
        float inv = 1.f / s;
        #pragma unroll
        for (int j = 0; j < 4; ++j)
            Ps[(wid*16 + lrow)*72 + j*16 + fr] = f2b(accs[j][r]*inv);
    }
    __syncthreads();

    floatx4 acco[4] = {};
    #pragma unroll
    for (int k0 = 0; k0 < 64; k0 += 32){
        short8 af = *(const short8*)(Ps + (wid*16 + fr)*72 + k0 + co);
        #pragma unroll
        for (int j = 0; j < 4; ++j){
            short8 bf = *(const short8*)(VT + (j*16 + fr)*72 + k0 + co);
            acco[j] = __builtin_amdgcn_mfma_f32_16x16x32_bf16(af, bf, acco[j], 0, 0, 0);
        }
    }
    #pragma unroll
    for (int r = 0; r < 4; ++r){
        int qi = wid*16 + quad*4 + r;
        if (qi < 49){
            #pragma unroll
            for (int j = 0; j < 4; ++j)
                outp[(size_t)(w*49 + qi)*CDIM + h*64 + j*16 + fr] = f2b(acco[j][r]);
        }
    }
}

// ---------- zero ----------
__global__ void zero_f32(float* __restrict__ p, int n){
    int i = blockIdx.x*256 + threadIdx.x;
    if (i < n) p[i] = 0.f;
}

// ---------- depthwise 3x3 + bn1(folded)+hswish + FUSED bn2-stats ----------
__global__ __launch_bounds__(256) void dwconv_s(const ushort_t* __restrict__ in,
                                                const float* __restrict__ wT,
                                                const float* __restrict__ sums1,
                                                const float* __restrict__ g1,
                                                const float* __restrict__ b1,
                                                ushort_t* __restrict__ out,
                                                float* __restrict__ sums2){
    const int cgl = threadIdx.x & 31;
    const int rp  = threadIdx.x >> 5;
    const int cg  = blockIdx.x*32 + cgl;       // [0,384)
    const int c   = cg*8;
    const int r0  = blockIdx.y*112;
    float sc[8], sh[8];
    #pragma unroll
    for (int e = 0; e < 8; ++e) bn_coef(sums1, HID, g1, b1, c+e, sc[e], sh[e]);
    float wv[9][8];
    #pragma unroll
    for (int kk = 0; kk < 9; ++kk){
        const float4* wp = (const float4*)(wT + kk*HID + c);
        float4 w0 = wp[0], w1 = wp[1];
        wv[kk][0]=w0.x; wv[kk][1]=w0.y; wv[kk][2]=w0.z; wv[kk][3]=w0.w;
        wv[kk][4]=w1.x; wv[kk][5]=w1.y; wv[kk][6]=w1.z; wv[kk][7]=w1.w;
    }
    float s[8] = {}, q[8] = {};
    for (int r = r0 + rp; r < r0 + 112; r += 8){
        int b = r / 196, p = r % 196;
        int y = p / 14,  x = p % 14;
        const uint4* inb = (const uint4*)(in + (size_t)b*196*HID);
        float acc[8] = {};
        #pragma unroll
        for (int ky = 0; ky < 3; ++ky){
            int yy = y + ky - 1;
            if ((unsigned)yy >= 14u) continue;
            #pragma unroll
            for (int kx = 0; kx < 3; ++kx){
                int xx = x + kx - 1;
                if ((unsigned)xx >= 14u) continue;
                uint4 u = inb[(yy*14 + xx)*384 + cg];
                float fin[8]; unpack8(u, fin);
                #pragma unroll
                for (int e = 0; e < 8; ++e)
                    acc[e] += hswish(fin[e]*sc[e] + sh[e]) * wv[ky*3 + kx][e];
            }
        }
        ((uint4*)out)[(size_t)r*384 + cg] = pack8(acc);
        #pragma unroll
        for (int e = 0; e < 8; ++e){ s[e] += acc[e]; q[e] += acc[e]*acc[e]; }
    }
    #pragma unroll
    for (int e = 0; e < 8; ++e){
        s[e] += __shfl_xor(s[e], 32, 64);
        q[e] += __shfl_xor(q[e], 32, 64);
    }
    __shared__ float red[4][32][17];
    const int wvv = threadIdx.x >> 6;
    if ((threadIdx.x & 32) == 0){
        #pragma unroll
        for (int e = 0; e < 8; ++e){
            red[wvv][cgl][e]   = s[e];
            red[wvv][cgl][8+e] = q[e];
        }
    }
    __syncthreads();
    #pragma unroll
    for (int k = 0; k < 2; ++k){
        int o = threadIdx.x*2 + k;
        int cgo = o >> 4, e = o & 15;
        float v = red[0][cgo][e] + red[1][cgo][e] + red[2][cgo][e] + red[3][cgo][e];
        int cc = blockIdx.x*256 + cgo*8 + (e & 7);
        atomicAdd(&sums2[(e < 8 ? 0 : HID) + cc], v);
    }
}

// ---------- SE (bn2 folded on read) ----------
__global__ __launch_bounds__(256) void se_mean_v(const ushort_t* __restrict__ X,
                                                 const float* __restrict__ sums2,
                                                 const float* __restrict__ g2,
                                                 const float* __restrict__ b2,
                                                 float* __restrict__ s){
    const int b   = blockIdx.x;
    const int cgl = threadIdx.x & 31;
    const int rp  = threadIdx.x >> 5;
    const int cg  = blockIdx.y*32 + cgl;
    const int c   = cg*8;
    float sc[8], sh[8];
    #pragma unroll
    for (int e = 0; e < 8; ++e) bn_coef(sums2, HID, g2, b2, c+e, sc[e], sh[e]);
    const uint4* Xb = (const uint4*)(X + (size_t)b*196*HID);
    float a[8] = {};
    for (int p = rp; p < 196; p += 8){
        uint4 u = Xb[(size_t)p*384 + cg];
        float f[8]; unpack8(u, f);
        #pragma unroll
        for (int e = 0; e < 8; ++e) a[e] += hswish(f[e]*sc[e] + sh[e]);
    }
    #pragma unroll
    for (int e = 0; e < 8; ++e) a[e] += __shfl_xor(a[e], 32, 64);
    __shared__ float red[4][32][9];
    const int wv = threadIdx.x >> 6;
    if ((threadIdx.x & 32) == 0){
        #pragma unroll
        for (int e = 0; e < 8; ++e) red[wv][cgl][e] = a[e];
    }
    __syncthreads();
    {
        int o = threadIdx.x;
        int cgo = o >> 3, e = o & 7;
        float v = red[0][cgo][e] + red[1][cgo][e] + red[2][cgo][e] + red[3][cgo][e];
        s[(size_t)b*HID + blockIdx.y*256 + cgo*8 + e] = v * (1.f/196.f);
    }
}
__global__ __launch_bounds__(256) void se_fc(const float* __restrict__ in,
                                             const float* __restrict__ w,
                                             const float* __restrict__ bias,
                                             float* __restrict__ out,
                                             int IN, int OUT, int mode){
    int wv   = (blockIdx.x*256 + threadIdx.x) >> 6;
    int lane = threadIdx.x & 63;
    if (wv >= OUT) return;
    const float* wr = w + (size_t)wv * IN;
    float acc[32];
    #pragma unroll
    for (int b = 0; b < 32; ++b) acc[b] = 0.f;
    for (int k = lane; k < IN; k += 64){
        float wval = wr[k];
        #pragma unroll
        for (int b = 0; b < 32; ++b)
            acc[b] += in[b*IN + k] * wval;
    }
    #pragma unroll
    for (int b = 0; b < 32; ++b){
        float v = acc[b];
        #pragma unroll
        for (int off = 32; off; off >>= 1) v += __shfl_down(v, off, 64);
        if (lane == 0){
            float a = v + bias[wv];
            if (mode == 0) a = fmaxf(a, 0.f);
            else           a = fminf(fmaxf(a + 3.f, 0.f), 6.f) * (1.f/6.f);
            out[b*OUT + wv] = a;
        }
    }
}
__global__ __launch_bounds__(256) void se_scale(ushort_t* __restrict__ X,
                                                const float* __restrict__ sums2,
                                                const float* __restrict__ g2,
                                                const float* __restrict__ b2,
                                                const float* __restrict__ s2){
    int idx = blockIdx.x*256 + threadIdx.x;
    if (idx >= MROWS * (HID/8)) return;
    int r = idx / (HID/8), c8 = idx % (HID/8);
    int b = r / 196;
    int c = c8*8;
    uint4 u = ((uint4*)X)[idx];
    float f[8]; unpack8(u, f);
    const float* sp = s2 + b*HID + c;
    #pragma unroll
    for (int e = 0; e < 8; ++e){
        float sc, sh;
        bn_coef(sums2, HID, g2, b2, c+e, sc, sh);
        f[e] = hswish(f[e]*sc + sh) * sp[e];
    }
    ((uint4*)X)[idx] = pack8(f);
}

// ---------- final: out = [cls | f_bf16 + h_bf16*sc + sh], bn3 folded ----------
__global__ __launch_bounds__(256) void final_k(const float4* __restrict__ xin,
                                               const ushort_t* __restrict__ fb,
                                               const ushort_t* __restrict__ hb4,
                                               const float* __restrict__ sums3,
                                               const float* __restrict__ g3,
                                               const float* __restrict__ b3,
                                               float4* __restrict__ outp){
    int idx = blockIdx.x*256 + threadIdx.x;        // over 32*197*96 (8-elem groups)
    if (idx >= 32*197*96) return;
    int b = idx / (197*96);
    int rem = idx % (197*96);
    int n = rem / 96, c8 = rem % 96;
    size_t obase = ((size_t)b*197 + n)*192 + c8*2;
    if (n == 0){
        outp[obase]     = xin[obase];
        outp[obase + 1] = xin[obase + 1];
        return;
    }
    size_t off = ((size_t)b*196 + n - 1)*96 + c8;
    uint4 fu = ((const uint4*)fb)[off];
    uint4 hu = ((const uint4*)hb4)[off];
    float fv[8], hv[8];
    unpack8(fu, fv); unpack8(hu, hv);
    int c = c8*8;
    float o[8];
    #pragma unroll
    for (int e = 0; e < 8; ++e){
        float sc, sh;
        bn_coef(sums3, CDIM, g3, b3, c+e, sc, sh);
        o[e] = fv[e] + hv[e]*sc + sh;
    }
    float4 o0 = {o[0], o[1], o[2], o[3]};
    float4 o1 = {o[4], o[5], o[6], o[7]};
    outp[obase]     = o0;
    outp[obase + 1] = o1;
}

extern "C" void kernel_launch(void* const* d_in, const int* in_sizes, int n_in,
                              void* d_out, int out_size, void* d_ws, size_t ws_size,
                              hipStream_t stream){
    const float* x      = (const float*)d_in[0];
    const float* w_qkv  = (const float*)d_in[1];
    const float* w_proj = (const float*)d_in[2];
    const float* b_proj = (const float*)d_in[3];
    const float* rpb    = (const float*)d_in[4];
    const float* pw1_w  = (const float*)d_in[5];
    const float* bn1_g  = (const float*)d_in[6];
    const float* bn1_b  = (const float*)d_in[7];
    const float* dw_w   = (const float*)d_in[8];
    const float* bn2_g  = (const float*)d_in[9];
    const float* bn2_b  = (const float*)d_in[10];
    const float* se_w1  = (const float*)d_in[11];
    const float* se_b1  = (const float*)d_in[12];
    const float* se_w2  = (const float*)d_in[13];
    const float* se_b2  = (const float*)d_in[14];
    const float* pw2_w  = (const float*)d_in[15];
    const float* bn3_g  = (const float*)d_in[16];
    const float* bn3_b  = (const float*)d_in[17];

    char* ws = (char*)d_ws;
    // Region A [0, 38535168): win[0,9.6M) | pw1b[9.6M,14.35M) | wprojb[14.35M,15.53M)
    //   | wqkvb[15.53M,19.07M) | bm[0,0.79M after win dead) -> hb (dwconv out, clobbers all)
    // Region B [38535168, 77070336): qkv[38.5M,67.4M) | attnb[67.4M,77.07M)
    //   -> ha (pw1 out, clobbers all) -> p[38.5M,57.8M) + hb4[57.8M,67.4M) after dwconv
    // Region C [77070336, 86704128): fb2 (proj out; lives to final_k)
    // High: pw2b[86.7M,91.4M) | dwwT | sums2|sums3|sums1 | s | s1 | s2
    ushort_t* win    = (ushort_t*)(ws + 0);
    ushort_t* pw1b   = (ushort_t*)(ws + 9633792);
    ushort_t* wprojb = (ushort_t*)(ws + 14352384);
    ushort_t* wqkvb  = (ushort_t*)(ws + 15532032);
    float*    bm     = (float*)(ws + 0);
    ushort_t* hb     = (ushort_t*)(ws + 0);
    ushort_t* qkv    = (ushort_t*)(ws + 38535168);
    ushort_t* attnb  = (ushort_t*)(ws + 67436544);
    ushort_t* ha     = (ushort_t*)(ws + 38535168);
    float*    p      = (float*)(ws + 38535168);
    ushort_t* hb4    = (ushort_t*)(ws + 57802752);
    ushort_t* fb2    = (ushort_t*)(ws + 77070336);
    ushort_t* pw2b   = (ushort_t*)(ws + 86704128);
    float*    dwwT   = (float*)(ws + 91422720);
    float*    sums2  = (float*)(ws + 91533312);
    float*    sums3  = (float*)(ws + 91557888);
    float*    sums1  = (float*)(ws + 91564032);
    float*    s      = (float*)(ws + 91588608);
    float*    s1     = (float*)(ws + 91981824);
    float*    s2     = (float*)(ws + 92080128);

    const int vec_rows = (MROWS*192 + 255)/256;
    const int vec_hid8 = (MROWS*(HID/8) + 255)/256;
    const int GY = 56;

    // prep: zero all bn sums (one launch, sums2|sums3|sums1 contiguous) + weight prep
    zero_f32<<<(2*HID + 2*CDIM + 2*HID + 255)/256, 256, 0, stream>>>(sums2, 2*HID + 2*CDIM + 2*HID);
    dw_transpose<<<(HID*9 + 255)/256, 256, 0, stream>>>(dw_w, dwwT);
    cvt_f2b<<<(QKV3*CDIM/4 + 255)/256, 256, 0, stream>>>((const float4*)w_qkv, (ushort4*)wqkvb, QKV3*CDIM/4);
    cvt_f2b<<<(CDIM*CDIM/4 + 255)/256, 256, 0, stream>>>((const float4*)w_proj, (ushort4*)wprojb, CDIM*CDIM/4);
    cvt_f2b<<<(HID*CDIM/4 + 255)/256, 256, 0, stream>>>((const float4*)pw1_w, (ushort4*)pw1b, HID*CDIM/4);
    cvt_f2b<<<(CDIM*HID/4 + 255)/256, 256, 0, stream>>>((const float4*)pw2_w, (ushort4*)pw2b, CDIM*HID/4);

    // attention half
    gather_win<<<vec_rows, 256, 0, stream>>>((const float4*)x, (ushort4*)win);
    gemm_bt<<<dim3(QKV3/128, GY), 256, 0, stream>>>(win, wqkvb, qkv, nullptr, MROWS, QKV3, CDIM, nullptr, nullptr, 0);
    bm_precompute<<<(12*4*64*64)/256, 256, 0, stream>>>(rpb, bm);    // win dead
    attn_mfma<<<dim3(12, 128), 256, 0, stream>>>(qkv, attnb, bm);
    gemm_bt64<<<dim3(CDIM/64, GY), 256, 0, stream>>>(attnb, wprojb, fb2, nullptr, MROWS, CDIM, CDIM, b_proj, nullptr, 1);

    // ConvFFN half
    gemm_bt<<<dim3(HID/128, GY), 256, 0, stream>>>(fb2, pw1b, ha, nullptr, MROWS, HID, CDIM, nullptr, sums1, 0);
    dwconv_s<<<dim3(12, GY), 256, 0, stream>>>(ha, dwwT, sums1, bn1_g, bn1_b, hb, sums2);   // bn1 folded + bn2-stats
    zero_f32<<<(MROWS*CDIM + 255)/256, 256, 0, stream>>>(p, MROWS*CDIM);                     // ha dead now
    se_mean_v<<<dim3(32, 12), 256, 0, stream>>>(hb, sums2, bn2_g, bn2_b, s);                // bn2 folded
    se_fc<<<dim3((CDIM*64)/256), 256, 0, stream>>>(s, se_w1, se_b1, s1, HID, CDIM, 0);
    se_fc<<<dim3((HID*64)/256), 256, 0, stream>>>(s1, se_w2, se_b2, s2, CDIM, HID, 1);
    se_scale<<<vec_hid8, 256, 0, stream>>>(hb, sums2, bn2_g, bn2_b, s2);                    // bn2 folded

    gemm_bt64_sk<<<dim3(CDIM/64, GY, 2), 256, 0, stream>>>(hb, pw2b, p, MROWS, CDIM, HID);  // split-K=2
    combine_k<<<dim3(3, 28), 256, 0, stream>>>(p, hb4, sums3);                              // bf16 + bn3 stats
    final_k<<<(32*197*96 + 255)/256, 256, 0, stream>>>((const float4*)x, fb2, hb4, sums3, bn3_g, bn3_b, (float4*)d_out);
}

// Round 10
// 511.905 us; speedup vs baseline: 1.1000x; 1.1000x over previous
//
#include <hip/hip_runtime.h>
#include <hip/hip_bf16.h>

typedef unsigned short ushort_t;
typedef unsigned int uint_t;
typedef short short8 __attribute__((ext_vector_type(8)));
typedef float floatx4 __attribute__((ext_vector_type(4)));

// ---------- bf16 helpers (raw ushort storage) ----------
__device__ inline float b2f(ushort_t u){
    uint_t v = ((uint_t)u) << 16;
    return __uint_as_float(v);
}
__device__ inline ushort_t f2b(float f){
    uint_t v = __float_as_uint(f);
    uint_t r = (v + 0x7FFFu + ((v >> 16) & 1u)) >> 16;  // RNE
    return (ushort_t)r;
}
__device__ inline void unpack8(uint4 u, float* f){
    uint_t w[4] = {u.x, u.y, u.z, u.w};
    #pragma unroll
    for (int i = 0; i < 4; ++i){
        f[2*i]   = __uint_as_float(w[i] << 16);
        f[2*i+1] = __uint_as_float(w[i] & 0xFFFF0000u);
    }
}
__device__ inline uint4 pack8(const float* f){
    uint4 o;
    uint_t w[4];
    #pragma unroll
    for (int i = 0; i < 4; ++i)
        w[i] = (uint_t)f2b(f[2*i]) | ((uint_t)f2b(f[2*i+1]) << 16);
    o.x = w[0]; o.y = w[1]; o.z = w[2]; o.w = w[3];
    return o;
}
__device__ inline ushort4 cvt4(float4 v){
    ushort4 o;
    o.x = f2b(v.x); o.y = f2b(v.y); o.z = f2b(v.z); o.w = f2b(v.w);
    return o;
}
__device__ inline float hswish(float y){
    return y * fminf(fmaxf(y + 3.f, 0.f), 6.f) * (1.f/6.f);
}

// ---------- constants ----------
#define MROWS 6272
#define CDIM  768
#define HID   3072
#define QKV3  2304

// swin window->spatial row map (with +3 roll): ri (window layout) -> dest row (b*196+p)
__device__ inline int scatter_row(int ri){
    int w  = ri / 49, t = ri % 49;
    int b  = w >> 2,  wi = w & 3;
    int wy = wi >> 1, wx = wi & 1;
    int ty = t / 7,   tx = t % 7;
    int yd = (wy*7 + ty + 3) % 14;
    int xd = (wx*7 + tx + 3) % 14;
    return b*196 + yd*14 + xd;
}

// bn scale/shift from raw sums (folded bn_finalize)
__device__ inline void bn_coef(const float* __restrict__ sums, int Cch,
                               const float* __restrict__ g, const float* __restrict__ b,
                               int c, float& sc, float& sh){
    float mean = sums[c] * (1.f/6272.f);
    float var  = sums[Cch + c] * (1.f/6272.f) - mean*mean;
    float s = g[c] * rsqrtf(var + 1e-5f);
    sc = s;
    sh = b[c] - mean*s;
}

// ---------- fp32 -> bf16 cast (weights) ----------
__global__ __launch_bounds__(256) void cvt_f2b(const float4* __restrict__ in,
                                               ushort4* __restrict__ out, int n4){
    int i = blockIdx.x * 256 + threadIdx.x;
    if (i < n4) out[i] = cvt4(in[i]);
}

// ---------- dw weight transpose: [3072][9] -> [9][3072] ----------
__global__ __launch_bounds__(256) void dw_transpose(const float* __restrict__ w,
                                                    float* __restrict__ wT){
    int i = blockIdx.x*256 + threadIdx.x;
    if (i < HID*9){ int c = i/9, k = i%9; wT[k*HID + c] = w[i]; }
}

// ---------- window gather: x fp32 (B,197,C) -> win bf16 (128*49, C), shifted ----------
__global__ __launch_bounds__(256) void gather_win(const float4* __restrict__ x,
                                                  ushort4* __restrict__ win){
    int idx = blockIdx.x * 256 + threadIdx.x;
    if (idx >= MROWS * 192) return;
    int r  = idx / 192, c4 = idx % 192;
    int w  = r / 49,  t  = r % 49;
    int b  = w >> 2,  wi = w & 3;
    int wy = wi >> 1, wx = wi & 1;
    int ty = t / 7,   tx = t % 7;
    int ys = (wy*7 + ty + 3) % 14;                       // roll(-3)
    int xs = (wx*7 + tx + 3) % 14;
    win[idx] = cvt4(x[(size_t)b*197*192 + (size_t)(1 + ys*14 + xs)*192 + c4]);
}

// ---------- MFMA GEMM 128x128 tile (qkv / pw1) ----------
__global__ __launch_bounds__(256) void gemm_bt(const ushort_t* __restrict__ A,
                                               const ushort_t* __restrict__ B,
                                               ushort_t* __restrict__ Cb,
                                               float* __restrict__ Cf,
                                               int M, int N, int K,
                                               const float* __restrict__ bias,
                                               float* __restrict__ stats,
                                               int scat){
    const int nx   = gridDim.x;
    int flat = blockIdx.y * nx + blockIdx.x;
    int xcd  = flat & 7;
    int k    = flat >> 3;
    int by   = xcd + 8 * (k / nx);
    int bx   = k % nx;
    if (by * 128 >= M) return;

    __shared__ __align__(16) ushort_t As[2][128*32];
    __shared__ __align__(16) ushort_t Bs[2][128*32];
    const int tid  = threadIdx.x;
    const int lane = tid & 63;
    const int wid  = tid >> 6;
    const int m0 = by * 128;
    const int n0 = bx * 128;
    const int wm = (wid >> 1) * 64;
    const int wn = (wid & 1) * 64;

    const int srow = (lane >> 2);
    const int scol = (((lane & 3) ^ ((lane >> 3) & 3)) * 8);

    floatx4 acc[4][4] = {};

    auto stage = [&](int buf, int k0){
        #pragma unroll
        for (int j = 0; j < 2; ++j){
            int ch  = wid*2 + j;
            const ushort_t* gA = A + (size_t)(m0 + ch*16 + srow)*K + k0 + scol;
            const ushort_t* gB = B + (size_t)(n0 + ch*16 + srow)*K + k0 + scol;
            __builtin_amdgcn_global_load_lds(
                (const __attribute__((address_space(1))) void*)gA,
                (__attribute__((address_space(3))) void*)(&As[buf][ch*512 + lane*8]), 16, 0, 0);
            __builtin_amdgcn_global_load_lds(
                (const __attribute__((address_space(1))) void*)gB,
                (__attribute__((address_space(3))) void*)(&Bs[buf][ch*512 + lane*8]), 16, 0, 0);
        }
    };

    const int NK = K >> 5;
    stage(0, 0);

    const int fr   = lane & 15;
    const int quad = lane >> 4;
    const int cosw = (quad ^ ((fr >> 1) & 3)) * 8;
    int cur = 0;
    for (int it = 0; it < NK; ++it){
        __builtin_amdgcn_sched_barrier(0);
        __builtin_amdgcn_s_barrier();
        if (it + 1 < NK){
            stage(cur ^ 1, (it + 1) << 5);
            asm volatile("s_waitcnt vmcnt(4)" ::: "memory");
        } else {
            asm volatile("s_waitcnt vmcnt(0)" ::: "memory");
        }
        __builtin_amdgcn_s_barrier();
        __builtin_amdgcn_sched_barrier(0);

        short8 af[4], bfr[4];
        #pragma unroll
        for (int i = 0; i < 4; ++i){
            af[i]  = *(const short8*)(&As[cur][(wm + i*16 + fr)*32 + cosw]);
            bfr[i] = *(const short8*)(&Bs[cur][(wn + i*16 + fr)*32 + cosw]);
        }
        #pragma unroll
        for (int i = 0; i < 4; ++i)
            #pragma unroll
            for (int j = 0; j < 4; ++j)
                acc[i][j] = __builtin_amdgcn_mfma_f32_16x16x32_bf16(af[i], bfr[j], acc[i][j], 0, 0, 0);
        cur ^= 1;
    }

    if (!scat && Cb){
        __syncthreads();
        ushort_t* Cspace = (wid < 2) ? &As[0][0] : &Bs[0][0];
        #pragma unroll
        for (int i = 0; i < 4; ++i){
            #pragma unroll
            for (int j = 0; j < 4; ++j){
                int col = wn + j*16 + fr;
                float bv = bias ? bias[n0 + col] : 0.f;
                #pragma unroll
                for (int r = 0; r < 4; ++r)
                    Cspace[(i*16 + quad*4 + r)*128 + (col ^ (quad << 4))] =
                        f2b(acc[i][j][r] + bv);
            }
        }
        __syncthreads();
        #pragma unroll
        for (int q = 0; q < 8; ++q){
            int fl  = q*256 + tid;
            int row = fl >> 4, u4c = fl & 15;
            const ushort_t* srcRow = (row < 64) ? (&As[0][0] + row*128)
                                                : (&Bs[0][0] + (row - 64)*128);
            int g = (row >> 2) & 3;
            *(uint4*)(Cb + (size_t)(m0 + row)*N + n0 + u4c*8) =
                *(const uint4*)(srcRow + ((u4c*8) ^ (g << 4)));
        }
    } else {
        #pragma unroll
        for (int i = 0; i < 4; ++i){
            int grow = m0 + wm + i*16 + quad*4;
            #pragma unroll
            for (int j = 0; j < 4; ++j){
                int gcol = n0 + wn + j*16 + fr;
                float bv = bias ? bias[gcol] : 0.f;
                if (scat){
                    #pragma unroll
                    for (int r = 0; r < 4; ++r){
                        float v = acc[i][j][r] + bv;
                        size_t off = (size_t)scatter_row(grow + r)*N + gcol;
                        if (Cf) Cf[off] = v;
                        Cb[off] = f2b(v);
                    }
                } else {
                    #pragma unroll
                    for (int r = 0; r < 4; ++r)
                        Cf[(size_t)(grow + r)*N + gcol] = acc[i][j][r] + bv;
                }
            }
        }
    }

    if (stats){
        #pragma unroll
        for (int j = 0; j < 4; ++j){
            int gcol = n0 + wn + j*16 + fr;
            float bv = bias ? bias[gcol] : 0.f;
            float sv = 0.f, sq = 0.f;
            #pragma unroll
            for (int i = 0; i < 4; ++i)
                #pragma unroll
                for (int r = 0; r < 4; ++r){
                    float v = acc[i][j][r] + bv;
                    sv += v; sq += v*v;
                }
            sv += __shfl_xor(sv, 16, 64);  sq += __shfl_xor(sq, 16, 64);
            sv += __shfl_xor(sv, 32, 64);  sq += __shfl_xor(sq, 32, 64);
            if (lane < 16){
                atomicAdd(&stats[gcol], sv);
                atomicAdd(&stats[N + gcol], sq);
            }
        }
    }
}

// ---------- MFMA GEMM 128x64 tile (proj / pw2) ----------
// Both output paths LDS-staged coalesced bf16; scat path remaps rows only
// (scatter_row permutes rows, columns stay contiguous).
__global__ __launch_bounds__(256) void gemm_bt64(const ushort_t* __restrict__ A,
                                                 const ushort_t* __restrict__ B,
                                                 ushort_t* __restrict__ Cb,
                                                 float* __restrict__ Cf,
                                                 int M, int N, int K,
                                                 const float* __restrict__ bias,
                                                 float* __restrict__ stats,
                                                 int scat){
    const int nx   = gridDim.x;
    int flat = blockIdx.y * nx + blockIdx.x;
    int xcd  = flat & 7;
    int k    = flat >> 3;
    int by   = xcd + 8 * (k / nx);
    int bx   = k % nx;
    if (by * 128 >= M) return;

    __shared__ __align__(16) ushort_t As[2][128*32];
    __shared__ __align__(16) ushort_t Bs[2][64*32];
    const int tid  = threadIdx.x;
    const int lane = tid & 63;
    const int wid  = tid >> 6;
    const int m0 = by * 128;
    const int n0 = bx * 64;
    const int wm = (wid >> 1) * 64;
    const int wn = (wid & 1) * 32;

    const int srow = (lane >> 2);
    const int scol = (((lane & 3) ^ ((lane >> 3) & 3)) * 8);

    floatx4 acc[4][2] = {};

    auto stage = [&](int buf, int k0){
        #pragma unroll
        for (int j = 0; j < 2; ++j){
            int ch = wid*2 + j;
            const ushort_t* gA = A + (size_t)(m0 + ch*16 + srow)*K + k0 + scol;
            __builtin_amdgcn_global_load_lds(
                (const __attribute__((address_space(1))) void*)gA,
                (__attribute__((address_space(3))) void*)(&As[buf][ch*512 + lane*8]), 16, 0, 0);
        }
        const ushort_t* gB = B + (size_t)(n0 + wid*16 + srow)*K + k0 + scol;
        __builtin_amdgcn_global_load_lds(
            (const __attribute__((address_space(1))) void*)gB,
            (__attribute__((address_space(3))) void*)(&Bs[buf][wid*512 + lane*8]), 16, 0, 0);
    };

    const int NK = K >> 5;
    stage(0, 0);

    const int fr   = lane & 15;
    const int quad = lane >> 4;
    const int cosw = (quad ^ ((fr >> 1) & 3)) * 8;
    int cur = 0;
    for (int it = 0; it < NK; ++it){
        __builtin_amdgcn_sched_barrier(0);
        __builtin_amdgcn_s_barrier();
        if (it + 1 < NK){
            stage(cur ^ 1, (it + 1) << 5);
            asm volatile("s_waitcnt vmcnt(3)" ::: "memory");
        } else {
            asm volatile("s_waitcnt vmcnt(0)" ::: "memory");
        }
        __builtin_amdgcn_s_barrier();
        __builtin_amdgcn_sched_barrier(0);

        short8 af[4], bfr[2];
        #pragma unroll
        for (int i = 0; i < 4; ++i)
            af[i]  = *(const short8*)(&As[cur][(wm + i*16 + fr)*32 + cosw]);
        #pragma unroll
        for (int j = 0; j < 2; ++j)
            bfr[j] = *(const short8*)(&Bs[cur][(wn + j*16 + fr)*32 + cosw]);
        #pragma unroll
        for (int i = 0; i < 4; ++i)
            #pragma unroll
            for (int j = 0; j < 2; ++j)
                acc[i][j] = __builtin_amdgcn_mfma_f32_16x16x32_bf16(af[i], bfr[j], acc[i][j], 0, 0, 0);
        cur ^= 1;
    }

    if (Cb){
        // LDS-staged coalesced bf16 store: C tile 128x64 in As[0].
        // scat=1: output row remapped via scatter_row (columns contiguous).
        __syncthreads();
        ushort_t* Cst = &As[0][0];
        #pragma unroll
        for (int i = 0; i < 4; ++i){
            #pragma unroll
            for (int j = 0; j < 2; ++j){
                int col = wn + j*16 + fr;
                float bv = bias ? bias[n0 + col] : 0.f;
                #pragma unroll
                for (int r = 0; r < 4; ++r)
                    Cst[(wm + i*16 + quad*4 + r)*64 + (col ^ (quad << 4))] =
                        f2b(acc[i][j][r] + bv);
            }
        }
        __syncthreads();
        #pragma unroll
        for (int q = 0; q < 4; ++q){
            int fl  = q*256 + tid;               // 1024 uint4s = 128 rows x 8
            int row = fl >> 3, u4c = fl & 7;
            int g = (row >> 2) & 3;
            int orow = scat ? scatter_row(m0 + row) : (m0 + row);
            *(uint4*)(Cb + (size_t)orow*N + n0 + u4c*8) =
                *(const uint4*)(Cst + row*64 + ((u4c*8) ^ (g << 4)));
        }
    } else {
        #pragma unroll
        for (int i = 0; i < 4; ++i){
            int grow = m0 + wm + i*16 + quad*4;
            #pragma unroll
            for (int j = 0; j < 2; ++j){
                int gcol = n0 + wn + j*16 + fr;
                float bv = bias ? bias[gcol] : 0.f;
                #pragma unroll
                for (int r = 0; r < 4; ++r)
                    Cf[(size_t)(grow + r)*N + gcol] = acc[i][j][r] + bv;
            }
        }
    }

    if (stats){
        #pragma unroll
        for (int j = 0; j < 2; ++j){
            int gcol = n0 + wn + j*16 + fr;
            float bv = bias ? bias[gcol] : 0.f;
            float sv = 0.f, sq = 0.f;
            #pragma unroll
            for (int i = 0; i < 4; ++i)
                #pragma unroll
                for (int r = 0; r < 4; ++r){
                    float v = acc[i][j][r] + bv;
                    sv += v; sq += v*v;
                }
            sv += __shfl_xor(sv, 16, 64);  sq += __shfl_xor(sq, 16, 64);
            sv += __shfl_xor(sv, 32, 64);  sq += __shfl_xor(sq, 32, 64);
            if (lane < 16){
                atomicAdd(&stats[gcol], sv);
                atomicAdd(&stats[N + gcol], sq);
            }
        }
    }
}

// ---------- bias+mask table ----------
__global__ __launch_bounds__(256) void bm_precompute(const float* __restrict__ rpb,
                                                     float* __restrict__ bm){
    int idx = blockIdx.x*256 + threadIdx.x;
    if (idx >= 12*4*64*64) return;
    int ki = idx & 63, qi = (idx >> 6) & 63, wi = (idx >> 12) & 3, h = idx >> 14;
    float v = -1e30f;
    if (qi < 49 && ki < 49){
        int qy = qi/7, qx = qi%7, ky = ki/7, kx = ki%7;
        int ridx = (qy - ky + 6)*13 + (qx - kx + 6);
        v = rpb[ridx*12 + h];
        int wy = wi >> 1, wx = wi & 1;
        int gqy = wy*7 + qy, gqx = wx*7 + qx, gky = wy*7 + ky, gkx = wx*7 + kx;
        int cq = ((gqy < 7) ? 0 : (gqy < 11 ? 1 : 2))*3 + ((gqx < 7) ? 0 : (gqx < 11 ? 1 : 2));
        int ck = ((gky < 7) ? 0 : (gky < 11 ? 1 : 2))*3 + ((gkx < 7) ? 0 : (gkx < 11 ? 1 : 2));
        if (cq != ck) v -= 100.f;
    }
    bm[idx] = v;
}

// ---------- MFMA attention ----------
__global__ __launch_bounds__(256) void attn_mfma(const ushort_t* __restrict__ qkv,
                                                 ushort_t* __restrict__ outp,
                                                 const float* __restrict__ bm){
    __shared__ __align__(16) ushort_t Ps[64*72];
    __shared__ __align__(16) ushort_t VT[64*72];
    const int tid = threadIdx.x, lane = tid & 63, wid = tid >> 6;
    const int h = blockIdx.x, w = blockIdx.y, wi = w & 3;
    const int fr = lane & 15, quad = lane >> 4, co = quad*8;

    for (int idx = tid; idx < 64*8; idx += 256){
        int k = idx >> 3, ng = idx & 7;
        uint4 u = {0u, 0u, 0u, 0u};
        if (k < 49) u = *(const uint4*)(qkv + (size_t)(w*49 + k)*QKV3 + 1536 + h*64 + ng*8);
        const ushort_t* vp = (const ushort_t*)&u;
        #pragma unroll
        for (int e = 0; e < 8; ++e) VT[(ng*8 + e)*72 + k] = vp[e];
    }
    __syncthreads();

    floatx4 accs[4] = {};
    const ushort_t* qbase = qkv + (size_t)(w*49 + wid*16 + fr)*QKV3 + h*64;
    #pragma unroll
    for (int k0 = 0; k0 < 64; k0 += 32){
        short8 af = *(const short8*)(qbase + k0 + co);
        #pragma unroll
        for (int j = 0; j < 4; ++j){
            const ushort_t* kbase = qkv + (size_t)(w*49 + j*16 + fr)*QKV3 + 768 + h*64;
            short8 bf = *(const short8*)(kbase + k0 + co);
            accs[j] = __builtin_amdgcn_mfma_f32_16x16x32_bf16(af, bf, accs[j], 0, 0, 0);
        }
    }

    const float* bmh = bm + (size_t)((h*4 + wi)*64 + wid*16)*64;
    #pragma unroll
    for (int r = 0; r < 4; ++r){
        int lrow = quad*4 + r;
        float m = -3e38f;
        #pragma unroll
        for (int j = 0; j < 4; ++j){
            float a = accs[j][r]*0.125f + bmh[lrow*64 + j*16 + fr];
            accs[j][r] = a;
            m = fmaxf(m, a);
        }
        #pragma unroll
        for (int off = 1; off < 16; off <<= 1) m = fmaxf(m, __shfl_xor(m, off, 64));
        float s = 0.f;
        #pragma unroll
        for (int j = 0; j < 4; ++j){
            float e = __expf(accs[j][r] - m);
            accs[j][r] = e; s += e;
        }
        #pragma unroll
        for (int off = 1; off < 16; off <<= 1) s += __shfl_xor(s, off, 64);
        float inv = 1.f / s;
        #pragma unroll
        for (int j = 0; j < 4; ++j)
            Ps[(wid*16 + lrow)*72 + j*16 + fr] = f2b(accs[j][r]*inv);
    }
    __syncthreads();

    floatx4 acco[4] = {};
    #pragma unroll
    for (int k0 = 0; k0 < 64; k0 += 32){
        short8 af = *(const short8*)(Ps + (wid*16 + fr)*72 + k0 + co);
        #pragma unroll
        for (int j = 0; j < 4; ++j){
            short8 bf = *(const short8*)(VT + (j*16 + fr)*72 + k0 + co);
            acco[j] = __builtin_amdgcn_mfma_f32_16x16x32_bf16(af, bf, acco[j], 0, 0, 0);
        }
    }
    #pragma unroll
    for (int r = 0; r < 4; ++r){
        int qi = wid*16 + quad*4 + r;
        if (qi < 49){
            #pragma unroll
            for (int j = 0; j < 4; ++j)
                outp[(size_t)(w*49 + qi)*CDIM + h*64 + j*16 + fr] = f2b(acco[j][r]);
        }
    }
}

// ---------- zero ----------
__global__ void zero_f32(float* __restrict__ p, int n){
    int i = blockIdx.x*256 + threadIdx.x;
    if (i < n) p[i] = 0.f;
}

// ---------- depthwise 3x3 + bn1(folded)+hswish + FUSED bn2-stats ----------
__global__ __launch_bounds__(256) void dwconv_s(const ushort_t* __restrict__ in,
                                                const float* __restrict__ wT,
                                                const float* __restrict__ sums1,
                                                const float* __restrict__ g1,
                                                const float* __restrict__ b1,
                                                ushort_t* __restrict__ out,
                                                float* __restrict__ sums2){
    const int cgl = threadIdx.x & 31;
    const int rp  = threadIdx.x >> 5;
    const int cg  = blockIdx.x*32 + cgl;       // [0,384)
    const int c   = cg*8;
    const int r0  = blockIdx.y*112;
    float sc[8], sh[8];
    #pragma unroll
    for (int e = 0; e < 8; ++e) bn_coef(sums1, HID, g1, b1, c+e, sc[e], sh[e]);
    float wv[9][8];
    #pragma unroll
    for (int kk = 0; kk < 9; ++kk){
        const float4* wp = (const float4*)(wT + kk*HID + c);
        float4 w0 = wp[0], w1 = wp[1];
        wv[kk][0]=w0.x; wv[kk][1]=w0.y; wv[kk][2]=w0.z; wv[kk][3]=w0.w;
        wv[kk][4]=w1.x; wv[kk][5]=w1.y; wv[kk][6]=w1.z; wv[kk][7]=w1.w;
    }
    float s[8] = {}, q[8] = {};
    for (int r = r0 + rp; r < r0 + 112; r += 8){
        int b = r / 196, p = r % 196;
        int y = p / 14,  x = p % 14;
        const uint4* inb = (const uint4*)(in + (size_t)b*196*HID);
        float acc[8] = {};
        #pragma unroll
        for (int ky = 0; ky < 3; ++ky){
            int yy = y + ky - 1;
            if ((unsigned)yy >= 14u) continue;
            #pragma unroll
            for (int kx = 0; kx < 3; ++kx){
                int xx = x + kx - 1;
                if ((unsigned)xx >= 14u) continue;
                uint4 u = inb[(yy*14 + xx)*384 + cg];
                float fin[8]; unpack8(u, fin);
                #pragma unroll
                for (int e = 0; e < 8; ++e)
                    acc[e] += hswish(fin[e]*sc[e] + sh[e]) * wv[ky*3 + kx][e];
            }
        }
        ((uint4*)out)[(size_t)r*384 + cg] = pack8(acc);
        #pragma unroll
        for (int e = 0; e < 8; ++e){ s[e] += acc[e]; q[e] += acc[e]*acc[e]; }
    }
    #pragma unroll
    for (int e = 0; e < 8; ++e){
        s[e] += __shfl_xor(s[e], 32, 64);
        q[e] += __shfl_xor(q[e], 32, 64);
    }
    __shared__ float red[4][32][17];
    const int wvv = threadIdx.x >> 6;
    if ((threadIdx.x & 32) == 0){
        #pragma unroll
        for (int e = 0; e < 8; ++e){
            red[wvv][cgl][e]   = s[e];
            red[wvv][cgl][8+e] = q[e];
        }
    }
    __syncthreads();
    #pragma unroll
    for (int k = 0; k < 2; ++k){
        int o = threadIdx.x*2 + k;
        int cgo = o >> 4, e = o & 15;
        float v = red[0][cgo][e] + red[1][cgo][e] + red[2][cgo][e] + red[3][cgo][e];
        int cc = blockIdx.x*256 + cgo*8 + (e & 7);
        atomicAdd(&sums2[(e < 8 ? 0 : HID) + cc], v);
    }
}

// ---------- SE (bn2 folded on read) ----------
__global__ __launch_bounds__(256) void se_mean_v(const ushort_t* __restrict__ X,
                                                 const float* __restrict__ sums2,
                                                 const float* __restrict__ g2,
                                                 const float* __restrict__ b2,
                                                 float* __restrict__ s){
    const int b   = blockIdx.x;
    const int cgl = threadIdx.x & 31;
    const int rp  = threadIdx.x >> 5;
    const int cg  = blockIdx.y*32 + cgl;
    const int c   = cg*8;
    float sc[8], sh[8];
    #pragma unroll
    for (int e = 0; e < 8; ++e) bn_coef(sums2, HID, g2, b2, c+e, sc[e], sh[e]);
    const uint4* Xb = (const uint4*)(X + (size_t)b*196*HID);
    float a[8] = {};
    for (int p = rp; p < 196; p += 8){
        uint4 u = Xb[(size_t)p*384 + cg];
        float f[8]; unpack8(u, f);
        #pragma unroll
        for (int e = 0; e < 8; ++e) a[e] += hswish(f[e]*sc[e] + sh[e]);
    }
    #pragma unroll
    for (int e = 0; e < 8; ++e) a[e] += __shfl_xor(a[e], 32, 64);
    __shared__ float red[4][32][9];
    const int wv = threadIdx.x >> 6;
    if ((threadIdx.x & 32) == 0){
        #pragma unroll
        for (int e = 0; e < 8; ++e) red[wv][cgl][e] = a[e];
    }
    __syncthreads();
    {
        int o = threadIdx.x;
        int cgo = o >> 3, e = o & 7;
        float v = red[0][cgo][e] + red[1][cgo][e] + red[2][cgo][e] + red[3][cgo][e];
        s[(size_t)b*HID + blockIdx.y*256 + cgo*8 + e] = v * (1.f/196.f);
    }
}
__global__ __launch_bounds__(256) void se_fc(const float* __restrict__ in,
                                             const float* __restrict__ w,
                                             const float* __restrict__ bias,
                                             float* __restrict__ out,
                                             int IN, int OUT, int mode){
    int wv   = (blockIdx.x*256 + threadIdx.x) >> 6;
    int lane = threadIdx.x & 63;
    if (wv >= OUT) return;
    const float* wr = w + (size_t)wv * IN;
    float acc[32];
    #pragma unroll
    for (int b = 0; b < 32; ++b) acc[b] = 0.f;
    for (int k = lane; k < IN; k += 64){
        float wval = wr[k];
        #pragma unroll
        for (int b = 0; b < 32; ++b)
            acc[b] += in[b*IN + k] * wval;
    }
    #pragma unroll
    for (int b = 0; b < 32; ++b){
        float v = acc[b];
        #pragma unroll
        for (int off = 32; off; off >>= 1) v += __shfl_down(v, off, 64);
        if (lane == 0){
            float a = v + bias[wv];
            if (mode == 0) a = fmaxf(a, 0.f);
            else           a = fminf(fmaxf(a + 3.f, 0.f), 6.f) * (1.f/6.f);
            out[b*OUT + wv] = a;
        }
    }
}
__global__ __launch_bounds__(256) void se_scale(ushort_t* __restrict__ X,
                                                const float* __restrict__ sums2,
                                                const float* __restrict__ g2,
                                                const float* __restrict__ b2,
                                                const float* __restrict__ s2){
    int idx = blockIdx.x*256 + threadIdx.x;
    if (idx >= MROWS * (HID/8)) return;
    int r = idx / (HID/8), c8 = idx % (HID/8);
    int b = r / 196;
    int c = c8*8;
    uint4 u = ((uint4*)X)[idx];
    float f[8]; unpack8(u, f);
    const float* sp = s2 + b*HID + c;
    #pragma unroll
    for (int e = 0; e < 8; ++e){
        float sc, sh;
        bn_coef(sums2, HID, g2, b2, c+e, sc, sh);
        f[e] = hswish(f[e]*sc + sh) * sp[e];
    }
    ((uint4*)X)[idx] = pack8(f);
}

// ---------- final: out = [cls | f_bf16 + h_bf16*sc + sh], bn3 folded ----------
__global__ __launch_bounds__(256) void final_k(const float4* __restrict__ xin,
                                               const ushort_t* __restrict__ fb,
                                               const ushort_t* __restrict__ hb4,
                                               const float* __restrict__ sums3,
                                               const float* __restrict__ g3,
                                               const float* __restrict__ b3,
                                               float4* __restrict__ outp){
    int idx = blockIdx.x*256 + threadIdx.x;        // over 32*197*96 (8-elem groups)
    if (idx >= 32*197*96) return;
    int b = idx / (197*96);
    int rem = idx % (197*96);
    int n = rem / 96, c8 = rem % 96;
    size_t obase = ((size_t)b*197 + n)*192 + c8*2;
    if (n == 0){
        outp[obase]     = xin[obase];
        outp[obase + 1] = xin[obase + 1];
        return;
    }
    size_t off = ((size_t)b*196 + n - 1)*96 + c8;
    uint4 fu = ((const uint4*)fb)[off];
    uint4 hu = ((const uint4*)hb4)[off];
    float fv[8], hv[8];
    unpack8(fu, fv); unpack8(hu, hv);
    int c = c8*8;
    float o[8];
    #pragma unroll
    for (int e = 0; e < 8; ++e){
        float sc, sh;
        bn_coef(sums3, CDIM, g3, b3, c+e, sc, sh);
        o[e] = fv[e] + hv[e]*sc + sh;
    }
    float4 o0 = {o[0], o[1], o[2], o[3]};
    float4 o1 = {o[4], o[5], o[6], o[7]};
    outp[obase]     = o0;
    outp[obase + 1] = o1;
}

extern "C" void kernel_launch(void* const* d_in, const int* in_sizes, int n_in,
                              void* d_out, int out_size, void* d_ws, size_t ws_size,
                              hipStream_t stream){
    const float* x      = (const float*)d_in[0];
    const float* w_qkv  = (const float*)d_in[1];
    const float* w_proj = (const float*)d_in[2];
    const float* b_proj = (const float*)d_in[3];
    const float* rpb    = (const float*)d_in[4];
    const float* pw1_w  = (const float*)d_in[5];
    const float* bn1_g  = (const float*)d_in[6];
    const float* bn1_b  = (const float*)d_in[7];
    const float* dw_w   = (const float*)d_in[8];
    const float* bn2_g  = (const float*)d_in[9];
    const float* bn2_b  = (const float*)d_in[10];
    const float* se_w1  = (const float*)d_in[11];
    const float* se_b1  = (const float*)d_in[12];
    const float* se_w2  = (const float*)d_in[13];
    const float* se_b2  = (const float*)d_in[14];
    const float* pw2_w  = (const float*)d_in[15];
    const float* bn3_g  = (const float*)d_in[16];
    const float* bn3_b  = (const float*)d_in[17];

    char* ws = (char*)d_ws;
    // r7 layout (verified): weights cast lazily where lifetimes allow.
    ushort_t* win    = (ushort_t*)(ws + 0);
    float*    bm     = (float*)(ws + 0);           // alias win: dead after qkv gemm
    ushort_t* hb     = (ushort_t*)(ws + 0);        // dwconv out (bm dead by then)
    ushort_t* qkv    = (ushort_t*)(ws + 9633792);
    ushort_t* pw1b   = (ushort_t*)(ws + 9633792);  // alias qkv: dead after attn
    ushort_t* wqkvb  = (ushort_t*)(ws + 38535168);
    ushort_t* attnb  = (ushort_t*)(ws + 38535168); // alias wqkvb: dead after qkv gemm
    ushort_t* ha     = (ushort_t*)(ws + 38535168); // alias attnb: dead after proj
    ushort_t* hb4    = (ushort_t*)(ws + 38535168); // alias ha: dead after dwconv
    ushort_t* wprojb = (ushort_t*)(ws + 48168960);
    ushort_t* pw2b   = (ushort_t*)(ws + 57802752);
    ushort_t* fb2    = (ushort_t*)(ws + 77070336); // proj bf16 out: pw1 A + residual
    float*    sums2  = (float*)(ws + 86704128);    // bn2 raw sums
    float*    sums3  = (float*)(ws + 86728704);    // bn3 raw sums
    float*    sums1  = (float*)(ws + 96337920);    // bn1 raw sums
    float*    s      = (float*)(ws + 96362496);
    float*    s1     = (float*)(ws + 96755712);
    float*    s2     = (float*)(ws + 96854016);
    float*    dwwT   = (float*)(ws + 96854016);    // alias s2: dead before se_fc writes s2

    const int vec_rows = (MROWS*192 + 255)/256;
    const int vec_hid8 = (MROWS*(HID/8) + 255)/256;
    const int GY = 56;

    // prep (off the data critical path)
    zero_f32<<<24, 256, 0, stream>>>(sums1, 2*HID);                  // bn1
    zero_f32<<<27, 256, 0, stream>>>(sums2, 2*HID + 2*CDIM);         // bn2+bn3 (contiguous)
    dw_transpose<<<(HID*9 + 255)/256, 256, 0, stream>>>(dw_w, dwwT);
    cvt_f2b<<<(QKV3*CDIM/4 + 255)/256, 256, 0, stream>>>((const float4*)w_qkv, (ushort4*)wqkvb, QKV3*CDIM/4);
    cvt_f2b<<<(CDIM*CDIM/4 + 255)/256, 256, 0, stream>>>((const float4*)w_proj, (ushort4*)wprojb, CDIM*CDIM/4);

    // attention half
    gather_win<<<vec_rows, 256, 0, stream>>>((const float4*)x, (ushort4*)win);
    gemm_bt<<<dim3(QKV3/128, GY), 256, 0, stream>>>(win, wqkvb, qkv, nullptr, MROWS, QKV3, CDIM, nullptr, nullptr, 0);
    bm_precompute<<<(12*4*64*64)/256, 256, 0, stream>>>(rpb, bm);    // win dead
    attn_mfma<<<dim3(12, 128), 256, 0, stream>>>(qkv, attnb, bm);
    cvt_f2b<<<(HID*CDIM/4 + 255)/256, 256, 0, stream>>>((const float4*)pw1_w, (ushort4*)pw1b, HID*CDIM/4);  // qkv dead
    gemm_bt64<<<dim3(CDIM/64, GY), 256, 0, stream>>>(attnb, wprojb, fb2, nullptr, MROWS, CDIM, CDIM, b_proj, nullptr, 1);

    // ConvFFN half
    gemm_bt<<<dim3(HID/128, GY), 256, 0, stream>>>(fb2, pw1b, ha, nullptr, MROWS, HID, CDIM, nullptr, sums1, 0);
    dwconv_s<<<dim3(12, GY), 256, 0, stream>>>(ha, dwwT, sums1, bn1_g, bn1_b, hb, sums2);   // bn1 folded + bn2-stats
    cvt_f2b<<<(CDIM*HID/4 + 255)/256, 256, 0, stream>>>((const float4*)pw2_w, (ushort4*)pw2b, CDIM*HID/4);  // ha dead
    se_mean_v<<<dim3(32, 12), 256, 0, stream>>>(hb, sums2, bn2_g, bn2_b, s);                // bn2 folded
    se_fc<<<dim3((CDIM*64)/256), 256, 0, stream>>>(s, se_w1, se_b1, s1, HID, CDIM, 0);
    se_fc<<<dim3((HID*64)/256), 256, 0, stream>>>(s1, se_w2, se_b2, s2, CDIM, HID, 1);
    se_scale<<<vec_hid8, 256, 0, stream>>>(hb, sums2, bn2_g, bn2_b, s2);                    // bn2 folded

    gemm_bt64<<<dim3(CDIM/64, GY), 256, 0, stream>>>(hb, pw2b, hb4, nullptr, MROWS, CDIM, HID, nullptr, sums3, 0);
    final_k<<<(32*197*96 + 255)/256, 256, 0, stream>>>((const float4*)x, fb2, hb4, sums3, bn3_g, bn3_b, (float4*)d_out);
}

// Round 11
// 498.061 us; speedup vs baseline: 1.1306x; 1.0278x over previous
//
#include <hip/hip_runtime.h>
#include <hip/hip_bf16.h>

typedef unsigned short ushort_t;
typedef unsigned int uint_t;
typedef short short8 __attribute__((ext_vector_type(8)));
typedef float floatx4 __attribute__((ext_vector_type(4)));

// ---------- bf16 helpers (raw ushort storage) ----------
__device__ inline float b2f(ushort_t u){
    uint_t v = ((uint_t)u) << 16;
    return __uint_as_float(v);
}
__device__ inline ushort_t f2b(float f){
    uint_t v = __float_as_uint(f);
    uint_t r = (v + 0x7FFFu + ((v >> 16) & 1u)) >> 16;  // RNE
    return (ushort_t)r;
}
__device__ inline void unpack8(uint4 u, float* f){
    uint_t w[4] = {u.x, u.y, u.z, u.w};
    #pragma unroll
    for (int i = 0; i < 4; ++i){
        f[2*i]   = __uint_as_float(w[i] << 16);
        f[2*i+1] = __uint_as_float(w[i] & 0xFFFF0000u);
    }
}
__device__ inline uint4 pack8(const float* f){
    uint4 o;
    uint_t w[4];
    #pragma unroll
    for (int i = 0; i < 4; ++i)
        w[i] = (uint_t)f2b(f[2*i]) | ((uint_t)f2b(f[2*i+1]) << 16);
    o.x = w[0]; o.y = w[1]; o.z = w[2]; o.w = w[3];
    return o;
}
__device__ inline ushort4 cvt4(float4 v){
    ushort4 o;
    o.x = f2b(v.x); o.y = f2b(v.y); o.z = f2b(v.z); o.w = f2b(v.w);
    return o;
}
__device__ inline float hswish(float y){
    return y * fminf(fmaxf(y + 3.f, 0.f), 6.f) * (1.f/6.f);
}

// ---------- constants ----------
#define MROWS 6272
#define CDIM  768
#define HID   3072
#define QKV3  2304

// swin window->spatial row map (with +3 roll): ri (window layout) -> dest row (b*196+p)
__device__ inline int scatter_row(int ri){
    int w  = ri / 49, t = ri % 49;
    int b  = w >> 2,  wi = w & 3;
    int wy = wi >> 1, wx = wi & 1;
    int ty = t / 7,   tx = t % 7;
    int yd = (wy*7 + ty + 3) % 14;
    int xd = (wx*7 + tx + 3) % 14;
    return b*196 + yd*14 + xd;
}

// bn scale/shift from raw sums (folded bn_finalize)
__device__ inline void bn_coef(const float* __restrict__ sums, int Cch,
                               const float* __restrict__ g, const float* __restrict__ b,
                               int c, float& sc, float& sh){
    float mean = sums[c] * (1.f/6272.f);
    float var  = sums[Cch + c] * (1.f/6272.f) - mean*mean;
    float s = g[c] * rsqrtf(var + 1e-5f);
    sc = s;
    sh = b[c] - mean*s;
}

// ---------- fused prep: zeros + dw transpose + 4 weight casts + gather + bias/mask ----------
// Block ranges (each job guarded): 24|30|108|1728|576|2304|2304|4704|768 = 12546 blocks.
__global__ __launch_bounds__(256) void prep_k(const float4* __restrict__ x,
                                              const float4* __restrict__ w_qkv,
                                              const float4* __restrict__ w_proj,
                                              const float4* __restrict__ pw1_w,
                                              const float4* __restrict__ pw2_w,
                                              const float* __restrict__ dw_w,
                                              const float* __restrict__ rpb,
                                              float* __restrict__ sums1,
                                              float* __restrict__ sums23,
                                              float* __restrict__ dwwT,
                                              ushort4* __restrict__ wqkvb,
                                              ushort4* __restrict__ wprojb,
                                              ushort4* __restrict__ pw1b,
                                              ushort4* __restrict__ pw2b,
                                              ushort4* __restrict__ win,
                                              float* __restrict__ bm){
    int bid = blockIdx.x;
    const int t = threadIdx.x;
    if (bid < 24){ int i = bid*256 + t; if (i < 2*HID) sums1[i] = 0.f; return; }
    bid -= 24;
    if (bid < 30){ int i = bid*256 + t; if (i < 2*HID + 2*CDIM) sums23[i] = 0.f; return; }
    bid -= 30;
    if (bid < 108){
        int i = bid*256 + t;
        if (i < HID*9){ int c = i/9, k = i%9; dwwT[k*HID + c] = dw_w[i]; }
        return;
    }
    bid -= 108;
    if (bid < 1728){ int i = bid*256 + t; wqkvb[i] = cvt4(w_qkv[i]); return; }   // 442368 exact
    bid -= 1728;
    if (bid < 576){ int i = bid*256 + t; wprojb[i] = cvt4(w_proj[i]); return; }  // 147456 exact
    bid -= 576;
    if (bid < 2304){ int i = bid*256 + t; pw1b[i] = cvt4(pw1_w[i]); return; }    // 589824 exact
    bid -= 2304;
    if (bid < 2304){ int i = bid*256 + t; pw2b[i] = cvt4(pw2_w[i]); return; }
    bid -= 2304;
    if (bid < 4704){                                                              // gather: 1204224 exact
        int idx = bid*256 + t;
        int r  = idx / 192, c4 = idx % 192;
        int w  = r / 49,  tt = r % 49;
        int b  = w >> 2,  wi = w & 3;
        int wy = wi >> 1, wx = wi & 1;
        int ty = tt / 7,  tx = tt % 7;
        int ys = (wy*7 + ty + 3) % 14;
        int xs = (wx*7 + tx + 3) % 14;
        win[idx] = cvt4(x[(size_t)b*197*192 + (size_t)(1 + ys*14 + xs)*192 + c4]);
        return;
    }
    bid -= 4704;
    {                                                                             // bm: 196608 exact
        int idx = bid*256 + t;
        int ki = idx & 63, qi = (idx >> 6) & 63, wi = (idx >> 12) & 3, h = idx >> 14;
        float v = -1e30f;
        if (qi < 49 && ki < 49){
            int qy = qi/7, qx = qi%7, ky = ki/7, kx = ki%7;
            int ridx = (qy - ky + 6)*13 + (qx - kx + 6);
            v = rpb[ridx*12 + h];
            int wy = wi >> 1, wx = wi & 1;
            int gqy = wy*7 + qy, gqx = wx*7 + qx, gky = wy*7 + ky, gkx = wx*7 + kx;
            int cq = ((gqy < 7) ? 0 : (gqy < 11 ? 1 : 2))*3 + ((gqx < 7) ? 0 : (gqx < 11 ? 1 : 2));
            int ck = ((gky < 7) ? 0 : (gky < 11 ? 1 : 2))*3 + ((gkx < 7) ? 0 : (gkx < 11 ? 1 : 2));
            if (cq != ck) v -= 100.f;
        }
        bm[idx] = v;
    }
}

// ---------- MFMA GEMM 128x128 tile (qkv / pw1) ----------
__global__ __launch_bounds__(256) void gemm_bt(const ushort_t* __restrict__ A,
                                               const ushort_t* __restrict__ B,
                                               ushort_t* __restrict__ Cb,
                                               float* __restrict__ Cf,
                                               int M, int N, int K,
                                               const float* __restrict__ bias,
                                               float* __restrict__ stats,
                                               int scat){
    const int nx   = gridDim.x;
    int flat = blockIdx.y * nx + blockIdx.x;
    int xcd  = flat & 7;
    int k    = flat >> 3;
    int by   = xcd + 8 * (k / nx);
    int bx   = k % nx;
    if (by * 128 >= M) return;

    __shared__ __align__(16) ushort_t As[2][128*32];
    __shared__ __align__(16) ushort_t Bs[2][128*32];
    const int tid  = threadIdx.x;
    const int lane = tid & 63;
    const int wid  = tid >> 6;
    const int m0 = by * 128;
    const int n0 = bx * 128;
    const int wm = (wid >> 1) * 64;
    const int wn = (wid & 1) * 64;

    const int srow = (lane >> 2);
    const int scol = (((lane & 3) ^ ((lane >> 3) & 3)) * 8);

    floatx4 acc[4][4] = {};

    auto stage = [&](int buf, int k0){
        #pragma unroll
        for (int j = 0; j < 2; ++j){
            int ch  = wid*2 + j;
            const ushort_t* gA = A + (size_t)(m0 + ch*16 + srow)*K + k0 + scol;
            const ushort_t* gB = B + (size_t)(n0 + ch*16 + srow)*K + k0 + scol;
            __builtin_amdgcn_global_load_lds(
                (const __attribute__((address_space(1))) void*)gA,
                (__attribute__((address_space(3))) void*)(&As[buf][ch*512 + lane*8]), 16, 0, 0);
            __builtin_amdgcn_global_load_lds(
                (const __attribute__((address_space(1))) void*)gB,
                (__attribute__((address_space(3))) void*)(&Bs[buf][ch*512 + lane*8]), 16, 0, 0);
        }
    };

    const int NK = K >> 5;
    stage(0, 0);

    const int fr   = lane & 15;
    const int quad = lane >> 4;
    const int cosw = (quad ^ ((fr >> 1) & 3)) * 8;
    int cur = 0;
    for (int it = 0; it < NK; ++it){
        __builtin_amdgcn_sched_barrier(0);
        __builtin_amdgcn_s_barrier();
        if (it + 1 < NK){
            stage(cur ^ 1, (it + 1) << 5);
            asm volatile("s_waitcnt vmcnt(4)" ::: "memory");
        } else {
            asm volatile("s_waitcnt vmcnt(0)" ::: "memory");
        }
        __builtin_amdgcn_s_barrier();
        __builtin_amdgcn_sched_barrier(0);

        short8 af[4], bfr[4];
        #pragma unroll
        for (int i = 0; i < 4; ++i){
            af[i]  = *(const short8*)(&As[cur][(wm + i*16 + fr)*32 + cosw]);
            bfr[i] = *(const short8*)(&Bs[cur][(wn + i*16 + fr)*32 + cosw]);
        }
        #pragma unroll
        for (int i = 0; i < 4; ++i)
            #pragma unroll
            for (int j = 0; j < 4; ++j)
                acc[i][j] = __builtin_amdgcn_mfma_f32_16x16x32_bf16(af[i], bfr[j], acc[i][j], 0, 0, 0);
        cur ^= 1;
    }

    if (!scat && Cb){
        __syncthreads();
        ushort_t* Cspace = (wid < 2) ? &As[0][0] : &Bs[0][0];
        #pragma unroll
        for (int i = 0; i < 4; ++i){
            #pragma unroll
            for (int j = 0; j < 4; ++j){
                int col = wn + j*16 + fr;
                float bv = bias ? bias[n0 + col] : 0.f;
                #pragma unroll
                for (int r = 0; r < 4; ++r)
                    Cspace[(i*16 + quad*4 + r)*128 + (col ^ (quad << 4))] =
                        f2b(acc[i][j][r] + bv);
            }
        }
        __syncthreads();
        #pragma unroll
        for (int q = 0; q < 8; ++q){
            int fl  = q*256 + tid;
            int row = fl >> 4, u4c = fl & 15;
            const ushort_t* srcRow = (row < 64) ? (&As[0][0] + row*128)
                                                : (&Bs[0][0] + (row - 64)*128);
            int g = (row >> 2) & 3;
            *(uint4*)(Cb + (size_t)(m0 + row)*N + n0 + u4c*8) =
                *(const uint4*)(srcRow + ((u4c*8) ^ (g << 4)));
        }
    } else {
        #pragma unroll
        for (int i = 0; i < 4; ++i){
            int grow = m0 + wm + i*16 + quad*4;
            #pragma unroll
            for (int j = 0; j < 4; ++j){
                int gcol = n0 + wn + j*16 + fr;
                float bv = bias ? bias[gcol] : 0.f;
                if (scat){
                    #pragma unroll
                    for (int r = 0; r < 4; ++r){
                        float v = acc[i][j][r] + bv;
                        size_t off = (size_t)scatter_row(grow + r)*N + gcol;
                        if (Cf) Cf[off] = v;
                        Cb[off] = f2b(v);
                    }
                } else {
                    #pragma unroll
                    for (int r = 0; r < 4; ++r)
                        Cf[(size_t)(grow + r)*N + gcol] = acc[i][j][r] + bv;
                }
            }
        }
    }

    if (stats){
        #pragma unroll
        for (int j = 0; j < 4; ++j){
            int gcol = n0 + wn + j*16 + fr;
            float bv = bias ? bias[gcol] : 0.f;
            float sv = 0.f, sq = 0.f;
            #pragma unroll
            for (int i = 0; i < 4; ++i)
                #pragma unroll
                for (int r = 0; r < 4; ++r){
                    float v = acc[i][j][r] + bv;
                    sv += v; sq += v*v;
                }
            sv += __shfl_xor(sv, 16, 64);  sq += __shfl_xor(sq, 16, 64);
            sv += __shfl_xor(sv, 32, 64);  sq += __shfl_xor(sq, 32, 64);
            if (lane < 16){
                atomicAdd(&stats[gcol], sv);
                atomicAdd(&stats[N + gcol], sq);
            }
        }
    }
}

// ---------- MFMA GEMM 128x64 tile (proj / pw2) ----------
// Both output paths LDS-staged coalesced bf16; scat path remaps rows only.
__global__ __launch_bounds__(256) void gemm_bt64(const ushort_t* __restrict__ A,
                                                 const ushort_t* __restrict__ B,
                                                 ushort_t* __restrict__ Cb,
                                                 float* __restrict__ Cf,
                                                 int M, int N, int K,
                                                 const float* __restrict__ bias,
                                                 float* __restrict__ stats,
                                                 int scat){
    const int nx   = gridDim.x;
    int flat = blockIdx.y * nx + blockIdx.x;
    int xcd  = flat & 7;
    int k    = flat >> 3;
    int by   = xcd + 8 * (k / nx);
    int bx   = k % nx;
    if (by * 128 >= M) return;

    __shared__ __align__(16) ushort_t As[2][128*32];
    __shared__ __align__(16) ushort_t Bs[2][64*32];
    const int tid  = threadIdx.x;
    const int lane = tid & 63;
    const int wid  = tid >> 6;
    const int m0 = by * 128;
    const int n0 = bx * 64;
    const int wm = (wid >> 1) * 64;
    const int wn = (wid & 1) * 32;

    const int srow = (lane >> 2);
    const int scol = (((lane & 3) ^ ((lane >> 3) & 3)) * 8);

    floatx4 acc[4][2] = {};

    auto stage = [&](int buf, int k0){
        #pragma unroll
        for (int j = 0; j < 2; ++j){
            int ch = wid*2 + j;
            const ushort_t* gA = A + (size_t)(m0 + ch*16 + srow)*K + k0 + scol;
            __builtin_amdgcn_global_load_lds(
                (const __attribute__((address_space(1))) void*)gA,
                (__attribute__((address_space(3))) void*)(&As[buf][ch*512 + lane*8]), 16, 0, 0);
        }
        const ushort_t* gB = B + (size_t)(n0 + wid*16 + srow)*K + k0 + scol;
        __builtin_amdgcn_global_load_lds(
            (const __attribute__((address_space(1))) void*)gB,
            (__attribute__((address_space(3))) void*)(&Bs[buf][wid*512 + lane*8]), 16, 0, 0);
    };

    const int NK = K >> 5;
    stage(0, 0);

    const int fr   = lane & 15;
    const int quad = lane >> 4;
    const int cosw = (quad ^ ((fr >> 1) & 3)) * 8;
    int cur = 0;
    for (int it = 0; it < NK; ++it){
        __builtin_amdgcn_sched_barrier(0);
        __builtin_amdgcn_s_barrier();
        if (it + 1 < NK){
            stage(cur ^ 1, (it + 1) << 5);
            asm volatile("s_waitcnt vmcnt(3)" ::: "memory");
        } else {
            asm volatile("s_waitcnt vmcnt(0)" ::: "memory");
        }
        __builtin_amdgcn_s_barrier();
        __builtin_amdgcn_sched_barrier(0);

        short8 af[4], bfr[2];
        #pragma unroll
        for (int i = 0; i < 4; ++i)
            af[i]  = *(const short8*)(&As[cur][(wm + i*16 + fr)*32 + cosw]);
        #pragma unroll
        for (int j = 0; j < 2; ++j)
            bfr[j] = *(const short8*)(&Bs[cur][(wn + j*16 + fr)*32 + cosw]);
        #pragma unroll
        for (int i = 0; i < 4; ++i)
            #pragma unroll
            for (int j = 0; j < 2; ++j)
                acc[i][j] = __builtin_amdgcn_mfma_f32_16x16x32_bf16(af[i], bfr[j], acc[i][j], 0, 0, 0);
        cur ^= 1;
    }

    if (Cb){
        __syncthreads();
        ushort_t* Cst = &As[0][0];
        #pragma unroll
        for (int i = 0; i < 4; ++i){
            #pragma unroll
            for (int j = 0; j < 2; ++j){
                int col = wn + j*16 + fr;
                float bv = bias ? bias[n0 + col] : 0.f;
                #pragma unroll
                for (int r = 0; r < 4; ++r)
                    Cst[(wm + i*16 + quad*4 + r)*64 + (col ^ (quad << 4))] =
                        f2b(acc[i][j][r] + bv);
            }
        }
        __syncthreads();
        #pragma unroll
        for (int q = 0; q < 4; ++q){
            int fl  = q*256 + tid;               // 1024 uint4s = 128 rows x 8
            int row = fl >> 3, u4c = fl & 7;
            int g = (row >> 2) & 3;
            int orow = scat ? scatter_row(m0 + row) : (m0 + row);
            *(uint4*)(Cb + (size_t)orow*N + n0 + u4c*8) =
                *(const uint4*)(Cst + row*64 + ((u4c*8) ^ (g << 4)));
        }
    } else {
        #pragma unroll
        for (int i = 0; i < 4; ++i){
            int grow = m0 + wm + i*16 + quad*4;
            #pragma unroll
            for (int j = 0; j < 2; ++j){
                int gcol = n0 + wn + j*16 + fr;
                float bv = bias ? bias[gcol] : 0.f;
                #pragma unroll
                for (int r = 0; r < 4; ++r)
                    Cf[(size_t)(grow + r)*N + gcol] = acc[i][j][r] + bv;
            }
        }
    }

    if (stats){
        #pragma unroll
        for (int j = 0; j < 2; ++j){
            int gcol = n0 + wn + j*16 + fr;
            float bv = bias ? bias[gcol] : 0.f;
            float sv = 0.f, sq = 0.f;
            #pragma unroll
            for (int i = 0; i < 4; ++i)
                #pragma unroll
                for (int r = 0; r < 4; ++r){
                    float v = acc[i][j][r] + bv;
                    sv += v; sq += v*v;
                }
            sv += __shfl_xor(sv, 16, 64);  sq += __shfl_xor(sq, 16, 64);
            sv += __shfl_xor(sv, 32, 64);  sq += __shfl_xor(sq, 32, 64);
            if (lane < 16){
                atomicAdd(&stats[gcol], sv);
                atomicAdd(&stats[N + gcol], sq);
            }
        }
    }
}

// ---------- MFMA attention ----------
__global__ __launch_bounds__(256) void attn_mfma(const ushort_t* __restrict__ qkv,
                                                 ushort_t* __restrict__ outp,
                                                 const float* __restrict__ bm){
    __shared__ __align__(16) ushort_t Ps[64*72];
    __shared__ __align__(16) ushort_t VT[64*72];
    const int tid = threadIdx.x, lane = tid & 63, wid = tid >> 6;
    const int h = blockIdx.x, w = blockIdx.y, wi = w & 3;
    const int fr = lane & 15, quad = lane >> 4, co = quad*8;

    for (int idx = tid; idx < 64*8; idx += 256){
        int k = idx >> 3, ng = idx & 7;
        uint4 u = {0u, 0u, 0u, 0u};
        if (k < 49) u = *(const uint4*)(qkv + (size_t)(w*49 + k)*QKV3 + 1536 + h*64 + ng*8);
        const ushort_t* vp = (const ushort_t*)&u;
        #pragma unroll
        for (int e = 0; e < 8; ++e) VT[(ng*8 + e)*72 + k] = vp[e];
    }
    __syncthreads();

    floatx4 accs[4] = {};
    const ushort_t* qbase = qkv + (size_t)(w*49 + wid*16 + fr)*QKV3 + h*64;
    #pragma unroll
    for (int k0 = 0; k0 < 64; k0 += 32){
        short8 af = *(const short8*)(qbase + k0 + co);
        #pragma unroll
        for (int j = 0; j < 4; ++j){
            const ushort_t* kbase = qkv + (size_t)(w*49 + j*16 + fr)*QKV3 + 768 + h*64;
            short8 bf = *(const short8*)(kbase + k0 + co);
            accs[j] = __builtin_amdgcn_mfma_f32_16x16x32_bf16(af, bf, accs[j], 0, 0, 0);
        }
    }

    const float* bmh = bm + (size_t)((h*4 + wi)*64 + wid*16)*64;
    #pragma unroll
    for (int r = 0; r < 4; ++r){
        int lrow = quad*4 + r;
        float m = -3e38f;
        #pragma unroll
        for (int j = 0; j < 4; ++j){
            float a = accs[j][r]*0.125f + bmh[lrow*64 + j*16 + fr];
            accs[j][r] = a;
            m = fmaxf(m, a);
        }
        #pragma unroll
        for (int off = 1; off < 16; off <<= 1) m = fmaxf(m, __shfl_xor(m, off, 64));
        float s = 0.f;
        #pragma unroll
        for (int j = 0; j < 4; ++j){
            float e = __expf(accs[j][r] - m);
            accs[j][r] = e; s += e;
        }
        #pragma unroll
        for (int off = 1; off < 16; off <<= 1) s += __shfl_xor(s, off, 64);
        float inv = 1.f / s;
        #pragma unroll
        for (int j = 0; j < 4; ++j)
            Ps[(wid*16 + lrow)*72 + j*16 + fr] = f2b(accs[j][r]*inv);
    }
    __syncthreads();

    floatx4 acco[4] = {};
    #pragma unroll
    for (int k0 = 0; k0 < 64; k0 += 32){
        short8 af = *(const short8*)(Ps + (wid*16 + fr)*72 + k0 + co);
        #pragma unroll
        for (int j = 0; j < 4; ++j){
            short8 bf = *(const short8*)(VT + (j*16 + fr)*72 + k0 + co);
            acco[j] = __builtin_amdgcn_mfma_f32_16x16x32_bf16(af, bf, acco[j], 0, 0, 0);
        }
    }
    #pragma unroll
    for (int r = 0; r < 4; ++r){
        int qi = wid*16 + quad*4 + r;
        if (qi < 49){
            #pragma unroll
            for (int j = 0; j < 4; ++j)
                outp[(size_t)(w*49 + qi)*CDIM + h*64 + j*16 + fr] = f2b(acco[j][r]);
        }
    }
}

// ---------- depthwise 3x3 + bn1(folded)+hswish + FUSED bn2-stats ----------
__global__ __launch_bounds__(256) void dwconv_s(const ushort_t* __restrict__ in,
                                                const float* __restrict__ wT,
                                                const float* __restrict__ sums1,
                                                const float* __restrict__ g1,
                                                const float* __restrict__ b1,
                                                ushort_t* __restrict__ out,
                                                float* __restrict__ sums2){
    const int cgl = threadIdx.x & 31;
    const int rp  = threadIdx.x >> 5;
    const int cg  = blockIdx.x*32 + cgl;       // [0,384)
    const int c   = cg*8;
    const int r0  = blockIdx.y*112;
    float sc[8], sh[8];
    #pragma unroll
    for (int e = 0; e < 8; ++e) bn_coef(sums1, HID, g1, b1, c+e, sc[e], sh[e]);
    float wv[9][8];
    #pragma unroll
    for (int kk = 0; kk < 9; ++kk){
        const float4* wp = (const float4*)(wT + kk*HID + c);
        float4 w0 = wp[0], w1 = wp[1];
        wv[kk][0]=w0.x; wv[kk][1]=w0.y; wv[kk][2]=w0.z; wv[kk][3]=w0.w;
        wv[kk][4]=w1.x; wv[kk][5]=w1.y; wv[kk][6]=w1.z; wv[kk][7]=w1.w;
    }
    float s[8] = {}, q[8] = {};
    for (int r = r0 + rp; r < r0 + 112; r += 8){
        int b = r / 196, p = r % 196;
        int y = p / 14,  x = p % 14;
        const uint4* inb = (const uint4*)(in + (size_t)b*196*HID);
        float acc[8] = {};
        #pragma unroll
        for (int ky = 0; ky < 3; ++ky){
            int yy = y + ky - 1;
            if ((unsigned)yy >= 14u) continue;
            #pragma unroll
            for (int kx = 0; kx < 3; ++kx){
                int xx = x + kx - 1;
                if ((unsigned)xx >= 14u) continue;
                uint4 u = inb[(yy*14 + xx)*384 + cg];
                float fin[8]; unpack8(u, fin);
                #pragma unroll
                for (int e = 0; e < 8; ++e)
                    acc[e] += hswish(fin[e]*sc[e] + sh[e]) * wv[ky*3 + kx][e];
            }
        }
        ((uint4*)out)[(size_t)r*384 + cg] = pack8(acc);
        #pragma unroll
        for (int e = 0; e < 8; ++e){ s[e] += acc[e]; q[e] += acc[e]*acc[e]; }
    }
    #pragma unroll
    for (int e = 0; e < 8; ++e){
        s[e] += __shfl_xor(s[e], 32, 64);
        q[e] += __shfl_xor(q[e], 32, 64);
    }
    __shared__ float red[4][32][17];
    const int wvv = threadIdx.x >> 6;
    if ((threadIdx.x & 32) == 0){
        #pragma unroll
        for (int e = 0; e < 8; ++e){
            red[wvv][cgl][e]   = s[e];
            red[wvv][cgl][8+e] = q[e];
        }
    }
    __syncthreads();
    #pragma unroll
    for (int k = 0; k < 2; ++k){
        int o = threadIdx.x*2 + k;
        int cgo = o >> 4, e = o & 15;
        float v = red[0][cgo][e] + red[1][cgo][e] + red[2][cgo][e] + red[3][cgo][e];
        int cc = blockIdx.x*256 + cgo*8 + (e & 7);
        atomicAdd(&sums2[(e < 8 ? 0 : HID) + cc], v);
    }
}

// ---------- SE (bn2 folded on read) ----------
__global__ __launch_bounds__(256) void se_mean_v(const ushort_t* __restrict__ X,
                                                 const float* __restrict__ sums2,
                                                 const float* __restrict__ g2,
                                                 const float* __restrict__ b2,
                                                 float* __restrict__ s){
    const int b   = blockIdx.x;
    const int cgl = threadIdx.x & 31;
    const int rp  = threadIdx.x >> 5;
    const int cg  = blockIdx.y*32 + cgl;
    const int c   = cg*8;
    float sc[8], sh[8];
    #pragma unroll
    for (int e = 0; e < 8; ++e) bn_coef(sums2, HID, g2, b2, c+e, sc[e], sh[e]);
    const uint4* Xb = (const uint4*)(X + (size_t)b*196*HID);
    float a[8] = {};
    for (int p = rp; p < 196; p += 8){
        uint4 u = Xb[(size_t)p*384 + cg];
        float f[8]; unpack8(u, f);
        #pragma unroll
        for (int e = 0; e < 8; ++e) a[e] += hswish(f[e]*sc[e] + sh[e]);
    }
    #pragma unroll
    for (int e = 0; e < 8; ++e) a[e] += __shfl_xor(a[e], 32, 64);
    __shared__ float red[4][32][9];
    const int wv = threadIdx.x >> 6;
    if ((threadIdx.x & 32) == 0){
        #pragma unroll
        for (int e = 0; e < 8; ++e) red[wv][cgl][e] = a[e];
    }
    __syncthreads();
    {
        int o = threadIdx.x;
        int cgo = o >> 3, e = o & 7;
        float v = red[0][cgo][e] + red[1][cgo][e] + red[2][cgo][e] + red[3][cgo][e];
        s[(size_t)b*HID + blockIdx.y*256 + cgo*8 + e] = v * (1.f/196.f);
    }
}
__global__ __launch_bounds__(256) void se_fc(const float* __restrict__ in,
                                             const float* __restrict__ w,
                                             const float* __restrict__ bias,
                                             float* __restrict__ out,
                                             int IN, int OUT, int mode){
    int wv   = (blockIdx.x*256 + threadIdx.x) >> 6;
    int lane = threadIdx.x & 63;
    if (wv >= OUT) return;
    const float* wr = w + (size_t)wv * IN;
    float acc[32];
    #pragma unroll
    for (int b = 0; b < 32; ++b) acc[b] = 0.f;
    for (int k = lane; k < IN; k += 64){
        float wval = wr[k];
        #pragma unroll
        for (int b = 0; b < 32; ++b)
            acc[b] += in[b*IN + k] * wval;
    }
    #pragma unroll
    for (int b = 0; b < 32; ++b){
        float v = acc[b];
        #pragma unroll
        for (int off = 32; off; off >>= 1) v += __shfl_down(v, off, 64);
        if (lane == 0){
            float a = v + bias[wv];
            if (mode == 0) a = fmaxf(a, 0.f);
            else           a = fminf(fmaxf(a + 3.f, 0.f), 6.f) * (1.f/6.f);
            out[b*OUT + wv] = a;
        }
    }
}
__global__ __launch_bounds__(256) void se_scale(ushort_t* __restrict__ X,
                                                const float* __restrict__ sums2,
                                                const float* __restrict__ g2,
                                                const float* __restrict__ b2,
                                                const float* __restrict__ s2){
    int idx = blockIdx.x*256 + threadIdx.x;
    if (idx >= MROWS * (HID/8)) return;
    int r = idx / (HID/8), c8 = idx % (HID/8);
    int b = r / 196;
    int c = c8*8;
    uint4 u = ((uint4*)X)[idx];
    float f[8]; unpack8(u, f);
    const float* sp = s2 + b*HID + c;
    #pragma unroll
    for (int e = 0; e < 8; ++e){
        float sc, sh;
        bn_coef(sums2, HID, g2, b2, c+e, sc, sh);
        f[e] = hswish(f[e]*sc + sh) * sp[e];
    }
    ((uint4*)X)[idx] = pack8(f);
}

// ---------- final: out = [cls | f_bf16 + h_bf16*sc + sh], bn3 folded ----------
__global__ __launch_bounds__(256) void final_k(const float4* __restrict__ xin,
                                               const ushort_t* __restrict__ fb,
                                               const ushort_t* __restrict__ hb4,
                                               const float* __restrict__ sums3,
                                               const float* __restrict__ g3,
                                               const float* __restrict__ b3,
                                               float4* __restrict__ outp){
    int idx = blockIdx.x*256 + threadIdx.x;        // over 32*197*96 (8-elem groups)
    if (idx >= 32*197*96) return;
    int b = idx / (197*96);
    int rem = idx % (197*96);
    int n = rem / 96, c8 = rem % 96;
    size_t obase = ((size_t)b*197 + n)*192 + c8*2;
    if (n == 0){
        outp[obase]     = xin[obase];
        outp[obase + 1] = xin[obase + 1];
        return;
    }
    size_t off = ((size_t)b*196 + n - 1)*96 + c8;
    uint4 fu = ((const uint4*)fb)[off];
    uint4 hu = ((const uint4*)hb4)[off];
    float fv[8], hv[8];
    unpack8(fu, fv); unpack8(hu, hv);
    int c = c8*8;
    float o[8];
    #pragma unroll
    for (int e = 0; e < 8; ++e){
        float sc, sh;
        bn_coef(sums3, CDIM, g3, b3, c+e, sc, sh);
        o[e] = fv[e] + hv[e]*sc + sh;
    }
    float4 o0 = {o[0], o[1], o[2], o[3]};
    float4 o1 = {o[4], o[5], o[6], o[7]};
    outp[obase]     = o0;
    outp[obase + 1] = o1;
}

extern "C" void kernel_launch(void* const* d_in, const int* in_sizes, int n_in,
                              void* d_out, int out_size, void* d_ws, size_t ws_size,
                              hipStream_t stream){
    const float* x      = (const float*)d_in[0];
    const float* w_qkv  = (const float*)d_in[1];
    const float* w_proj = (const float*)d_in[2];
    const float* b_proj = (const float*)d_in[3];
    const float* rpb    = (const float*)d_in[4];
    const float* pw1_w  = (const float*)d_in[5];
    const float* bn1_g  = (const float*)d_in[6];
    const float* bn1_b  = (const float*)d_in[7];
    const float* dw_w   = (const float*)d_in[8];
    const float* bn2_g  = (const float*)d_in[9];
    const float* bn2_b  = (const float*)d_in[10];
    const float* se_w1  = (const float*)d_in[11];
    const float* se_b1  = (const float*)d_in[12];
    const float* se_w2  = (const float*)d_in[13];
    const float* se_b2  = (const float*)d_in[14];
    const float* pw2_w  = (const float*)d_in[15];
    const float* bn3_g  = (const float*)d_in[16];
    const float* bn3_b  = (const float*)d_in[17];

    char* ws = (char*)d_ws;
    // Lifetime map:
    //  [0, 9.63M):        win (prep) -> dead after qkv gemm -> hb (dwconv out)
    //  [9.63M, 38.54M):   qkv (qkv gemm -> attn)
    //  [38.54M, 48.17M):  wqkvb (prep) -> attnb (attn out) -> ha (pw1 out) -> hb4 (pw2 out)
    //  [48.17M, 49.35M):  wprojb (prep -> proj)
    //  [49.35M, 50.13M):  bm (prep -> attn; clobbered later by ha)
    //  [50.13M, 77.07M):  ha tail (pw1 out spans [38.54M, 77.07M))
    //  [77.07M, 86.70M):  fb2 (proj out; lives to final_k)
    //  [86.70M, 86.73M):  sums2 | sums3 (contiguous, zeroed in prep)
    //  [86.73M, 91.45M):  pw1b (prep -> pw1 gemm; untouched in between)
    //  [91.45M, 96.17M):  pw2b (prep -> pw2 gemm; untouched in between)
    //  [96.34M, ...):     sums1 | s | s1 | s2/dwwT
    ushort_t* win    = (ushort_t*)(ws + 0);
    ushort_t* hb     = (ushort_t*)(ws + 0);
    ushort_t* qkv    = (ushort_t*)(ws + 9633792);
    ushort_t* wqkvb  = (ushort_t*)(ws + 38535168);
    ushort_t* attnb  = (ushort_t*)(ws + 38535168);
    ushort_t* ha     = (ushort_t*)(ws + 38535168);
    ushort_t* hb4    = (ushort_t*)(ws + 38535168);
    ushort_t* wprojb = (ushort_t*)(ws + 48168960);
    float*    bm     = (float*)(ws + 49348608);
    ushort_t* fb2    = (ushort_t*)(ws + 77070336);
    float*    sums2  = (float*)(ws + 86704128);
    float*    sums3  = (float*)(ws + 86728704);
    ushort_t* pw1b   = (ushort_t*)(ws + 86734848);
    ushort_t* pw2b   = (ushort_t*)(ws + 91453440);
    float*    sums1  = (float*)(ws + 96337920);
    float*    s      = (float*)(ws + 96362496);
    float*    s1     = (float*)(ws + 96755712);
    float*    s2     = (float*)(ws + 96854016);
    float*    dwwT   = (float*)(ws + 96854016);    // alias s2: dead before se_fc writes s2

    const int vec_hid8 = (MROWS*(HID/8) + 255)/256;
    const int GY = 56;

    // single fused prep: zeros + dwT + 4 weight casts + window gather + bias/mask table
    prep_k<<<12546, 256, 0, stream>>>((const float4*)x, (const float4*)w_qkv,
                                      (const float4*)w_proj, (const float4*)pw1_w,
                                      (const float4*)pw2_w, dw_w, rpb,
                                      sums1, sums2, dwwT,
                                      (ushort4*)wqkvb, (ushort4*)wprojb,
                                      (ushort4*)pw1b, (ushort4*)pw2b,
                                      (ushort4*)win, bm);

    // attention half
    gemm_bt<<<dim3(QKV3/128, GY), 256, 0, stream>>>(win, wqkvb, qkv, nullptr, MROWS, QKV3, CDIM, nullptr, nullptr, 0);
    attn_mfma<<<dim3(12, 128), 256, 0, stream>>>(qkv, attnb, bm);
    gemm_bt64<<<dim3(CDIM/64, GY), 256, 0, stream>>>(attnb, wprojb, fb2, nullptr, MROWS, CDIM, CDIM, b_proj, nullptr, 1);

    // ConvFFN half
    gemm_bt<<<dim3(HID/128, GY), 256, 0, stream>>>(fb2, pw1b, ha, nullptr, MROWS, HID, CDIM, nullptr, sums1, 0);
    dwconv_s<<<dim3(12, GY), 256, 0, stream>>>(ha, dwwT, sums1, bn1_g, bn1_b, hb, sums2);   // bn1 folded + bn2-stats
    se_mean_v<<<dim3(32, 12), 256, 0, stream>>>(hb, sums2, bn2_g, bn2_b, s);                // bn2 folded
    se_fc<<<dim3((CDIM*64)/256), 256, 0, stream>>>(s, se_w1, se_b1, s1, HID, CDIM, 0);
    se_fc<<<dim3((HID*64)/256), 256, 0, stream>>>(s1, se_w2, se_b2, s2, CDIM, HID, 1);
    se_scale<<<vec_hid8, 256, 0, stream>>>(hb, sums2, bn2_g, bn2_b, s2);                    // bn2 folded

    gemm_bt64<<<dim3(CDIM/64, GY), 256, 0, stream>>>(hb, pw2b, hb4, nullptr, MROWS, CDIM, HID, nullptr, sums3, 0);
    final_k<<<(32*197*96 + 255)/256, 256, 0, stream>>>((const float4*)x, fb2, hb4, sums3, bn3_g, bn3_b, (float4*)d_out);
}

// Round 12
// 496.737 us; speedup vs baseline: 1.1336x; 1.0027x over previous
//
#include <hip/hip_runtime.h>
#include <hip/hip_bf16.h>

typedef unsigned short ushort_t;
typedef unsigned int uint_t;
typedef short short8 __attribute__((ext_vector_type(8)));
typedef float floatx4 __attribute__((ext_vector_type(4)));

// ---------- bf16 helpers (raw ushort storage) ----------
__device__ inline float b2f(ushort_t u){
    uint_t v = ((uint_t)u) << 16;
    return __uint_as_float(v);
}
__device__ inline ushort_t f2b(float f){
    uint_t v = __float_as_uint(f);
    uint_t r = (v + 0x7FFFu + ((v >> 16) & 1u)) >> 16;  // RNE
    return (ushort_t)r;
}
__device__ inline void unpack8(uint4 u, float* f){
    uint_t w[4] = {u.x, u.y, u.z, u.w};
    #pragma unroll
    for (int i = 0; i < 4; ++i){
        f[2*i]   = __uint_as_float(w[i] << 16);
        f[2*i+1] = __uint_as_float(w[i] & 0xFFFF0000u);
    }
}
__device__ inline uint4 pack8(const float* f){
    uint4 o;
    uint_t w[4];
    #pragma unroll
    for (int i = 0; i < 4; ++i)
        w[i] = (uint_t)f2b(f[2*i]) | ((uint_t)f2b(f[2*i+1]) << 16);
    o.x = w[0]; o.y = w[1]; o.z = w[2]; o.w = w[3];
    return o;
}
__device__ inline ushort4 cvt4(float4 v){
    ushort4 o;
    o.x = f2b(v.x); o.y = f2b(v.y); o.z = f2b(v.z); o.w = f2b(v.w);
    return o;
}
__device__ inline float hswish(float y){
    return y * fminf(fmaxf(y + 3.f, 0.f), 6.f) * (1.f/6.f);
}

// ---------- constants ----------
#define MROWS 6272
#define CDIM  768
#define HID   3072
#define QKV3  2304

// swin window->spatial row map (with +3 roll): ri (window layout) -> dest row (b*196+p)
__device__ inline int scatter_row(int ri){
    int w  = ri / 49, t = ri % 49;
    int b  = w >> 2,  wi = w & 3;
    int wy = wi >> 1, wx = wi & 1;
    int ty = t / 7,   tx = t % 7;
    int yd = (wy*7 + ty + 3) % 14;
    int xd = (wx*7 + tx + 3) % 14;
    return b*196 + yd*14 + xd;
}

// bn scale/shift from raw sums (folded bn_finalize)
__device__ inline void bn_coef(const float* __restrict__ sums, int Cch,
                               const float* __restrict__ g, const float* __restrict__ b,
                               int c, float& sc, float& sh){
    float mean = sums[c] * (1.f/6272.f);
    float var  = sums[Cch + c] * (1.f/6272.f) - mean*mean;
    float s = g[c] * rsqrtf(var + 1e-5f);
    sc = s;
    sh = b[c] - mean*s;
}

// ---------- fused prep: zeros + dw transpose + 4 weight casts + gather + bias/mask ----------
// Block ranges (each job guarded): 24|30|108|1728|576|2304|2304|4704|768 = 12546 blocks.
__global__ __launch_bounds__(256) void prep_k(const float4* __restrict__ x,
                                              const float4* __restrict__ w_qkv,
                                              const float4* __restrict__ w_proj,
                                              const float4* __restrict__ pw1_w,
                                              const float4* __restrict__ pw2_w,
                                              const float* __restrict__ dw_w,
                                              const float* __restrict__ rpb,
                                              float* __restrict__ sums1,
                                              float* __restrict__ sums23,
                                              float* __restrict__ dwwT,
                                              ushort4* __restrict__ wqkvb,
                                              ushort4* __restrict__ wprojb,
                                              ushort4* __restrict__ pw1b,
                                              ushort4* __restrict__ pw2b,
                                              ushort4* __restrict__ win,
                                              float* __restrict__ bm){
    int bid = blockIdx.x;
    const int t = threadIdx.x;
    if (bid < 24){ int i = bid*256 + t; if (i < 2*HID) sums1[i] = 0.f; return; }
    bid -= 24;
    if (bid < 30){ int i = bid*256 + t; if (i < 2*HID + 2*CDIM) sums23[i] = 0.f; return; }
    bid -= 30;
    if (bid < 108){
        int i = bid*256 + t;
        if (i < HID*9){ int c = i/9, k = i%9; dwwT[k*HID + c] = dw_w[i]; }
        return;
    }
    bid -= 108;
    if (bid < 1728){ int i = bid*256 + t; wqkvb[i] = cvt4(w_qkv[i]); return; }   // 442368 exact
    bid -= 1728;
    if (bid < 576){ int i = bid*256 + t; wprojb[i] = cvt4(w_proj[i]); return; }  // 147456 exact
    bid -= 576;
    if (bid < 2304){ int i = bid*256 + t; pw1b[i] = cvt4(pw1_w[i]); return; }    // 589824 exact
    bid -= 2304;
    if (bid < 2304){ int i = bid*256 + t; pw2b[i] = cvt4(pw2_w[i]); return; }
    bid -= 2304;
    if (bid < 4704){                                                              // gather: 1204224 exact
        int idx = bid*256 + t;
        int r  = idx / 192, c4 = idx % 192;
        int w  = r / 49,  tt = r % 49;
        int b  = w >> 2,  wi = w & 3;
        int wy = wi >> 1, wx = wi & 1;
        int ty = tt / 7,  tx = tt % 7;
        int ys = (wy*7 + ty + 3) % 14;
        int xs = (wx*7 + tx + 3) % 14;
        win[idx] = cvt4(x[(size_t)b*197*192 + (size_t)(1 + ys*14 + xs)*192 + c4]);
        return;
    }
    bid -= 4704;
    {                                                                             // bm: 196608 exact
        int idx = bid*256 + t;
        int ki = idx & 63, qi = (idx >> 6) & 63, wi = (idx >> 12) & 3, h = idx >> 14;
        float v = -1e30f;
        if (qi < 49 && ki < 49){
            int qy = qi/7, qx = qi%7, ky = ki/7, kx = ki%7;
            int ridx = (qy - ky + 6)*13 + (qx - kx + 6);
            v = rpb[ridx*12 + h];
            int wy = wi >> 1, wx = wi & 1;
            int gqy = wy*7 + qy, gqx = wx*7 + qx, gky = wy*7 + ky, gkx = wx*7 + kx;
            int cq = ((gqy < 7) ? 0 : (gqy < 11 ? 1 : 2))*3 + ((gqx < 7) ? 0 : (gqx < 11 ? 1 : 2));
            int ck = ((gky < 7) ? 0 : (gky < 11 ? 1 : 2))*3 + ((gkx < 7) ? 0 : (gkx < 11 ? 1 : 2));
            if (cq != ck) v -= 100.f;
        }
        bm[idx] = v;
    }
}

// ---------- MFMA GEMM 128x128 tile (qkv / pw1) ----------
__global__ __launch_bounds__(256) void gemm_bt(const ushort_t* __restrict__ A,
                                               const ushort_t* __restrict__ B,
                                               ushort_t* __restrict__ Cb,
                                               float* __restrict__ Cf,
                                               int M, int N, int K,
                                               const float* __restrict__ bias,
                                               float* __restrict__ stats,
                                               int scat){
    const int nx   = gridDim.x;
    int flat = blockIdx.y * nx + blockIdx.x;
    int xcd  = flat & 7;
    int k    = flat >> 3;
    int by   = xcd + 8 * (k / nx);
    int bx   = k % nx;
    if (by * 128 >= M) return;

    __shared__ __align__(16) ushort_t As[2][128*32];
    __shared__ __align__(16) ushort_t Bs[2][128*32];
    const int tid  = threadIdx.x;
    const int lane = tid & 63;
    const int wid  = tid >> 6;
    const int m0 = by * 128;
    const int n0 = bx * 128;
    const int wm = (wid >> 1) * 64;
    const int wn = (wid & 1) * 64;

    const int srow = (lane >> 2);
    const int scol = (((lane & 3) ^ ((lane >> 3) & 3)) * 8);

    floatx4 acc[4][4] = {};

    auto stage = [&](int buf, int k0){
        #pragma unroll
        for (int j = 0; j < 2; ++j){
            int ch  = wid*2 + j;
            const ushort_t* gA = A + (size_t)(m0 + ch*16 + srow)*K + k0 + scol;
            const ushort_t* gB = B + (size_t)(n0 + ch*16 + srow)*K + k0 + scol;
            __builtin_amdgcn_global_load_lds(
                (const __attribute__((address_space(1))) void*)gA,
                (__attribute__((address_space(3))) void*)(&As[buf][ch*512 + lane*8]), 16, 0, 0);
            __builtin_amdgcn_global_load_lds(
                (const __attribute__((address_space(1))) void*)gB,
                (__attribute__((address_space(3))) void*)(&Bs[buf][ch*512 + lane*8]), 16, 0, 0);
        }
    };

    const int NK = K >> 5;
    stage(0, 0);

    const int fr   = lane & 15;
    const int quad = lane >> 4;
    const int cosw = (quad ^ ((fr >> 1) & 3)) * 8;
    int cur = 0;
    for (int it = 0; it < NK; ++it){
        __builtin_amdgcn_sched_barrier(0);
        __builtin_amdgcn_s_barrier();
        if (it + 1 < NK){
            stage(cur ^ 1, (it + 1) << 5);
            asm volatile("s_waitcnt vmcnt(4)" ::: "memory");
        } else {
            asm volatile("s_waitcnt vmcnt(0)" ::: "memory");
        }
        __builtin_amdgcn_s_barrier();
        __builtin_amdgcn_sched_barrier(0);

        short8 af[4], bfr[4];
        #pragma unroll
        for (int i = 0; i < 4; ++i){
            af[i]  = *(const short8*)(&As[cur][(wm + i*16 + fr)*32 + cosw]);
            bfr[i] = *(const short8*)(&Bs[cur][(wn + i*16 + fr)*32 + cosw]);
        }
        #pragma unroll
        for (int i = 0; i < 4; ++i)
            #pragma unroll
            for (int j = 0; j < 4; ++j)
                acc[i][j] = __builtin_amdgcn_mfma_f32_16x16x32_bf16(af[i], bfr[j], acc[i][j], 0, 0, 0);
        cur ^= 1;
    }

    if (!scat && Cb){
        __syncthreads();
        ushort_t* Cspace = (wid < 2) ? &As[0][0] : &Bs[0][0];
        #pragma unroll
        for (int i = 0; i < 4; ++i){
            #pragma unroll
            for (int j = 0; j < 4; ++j){
                int col = wn + j*16 + fr;
                float bv = bias ? bias[n0 + col] : 0.f;
                #pragma unroll
                for (int r = 0; r < 4; ++r)
                    Cspace[(i*16 + quad*4 + r)*128 + (col ^ (quad << 4))] =
                        f2b(acc[i][j][r] + bv);
            }
        }
        __syncthreads();
        #pragma unroll
        for (int q = 0; q < 8; ++q){
            int fl  = q*256 + tid;
            int row = fl >> 4, u4c = fl & 15;
            const ushort_t* srcRow = (row < 64) ? (&As[0][0] + row*128)
                                                : (&Bs[0][0] + (row - 64)*128);
            int g = (row >> 2) & 3;
            *(uint4*)(Cb + (size_t)(m0 + row)*N + n0 + u4c*8) =
                *(const uint4*)(srcRow + ((u4c*8) ^ (g << 4)));
        }
    } else {
        #pragma unroll
        for (int i = 0; i < 4; ++i){
            int grow = m0 + wm + i*16 + quad*4;
            #pragma unroll
            for (int j = 0; j < 4; ++j){
                int gcol = n0 + wn + j*16 + fr;
                float bv = bias ? bias[gcol] : 0.f;
                if (scat){
                    #pragma unroll
                    for (int r = 0; r < 4; ++r){
                        float v = acc[i][j][r] + bv;
                        size_t off = (size_t)scatter_row(grow + r)*N + gcol;
                        if (Cf) Cf[off] = v;
                        Cb[off] = f2b(v);
                    }
                } else {
                    #pragma unroll
                    for (int r = 0; r < 4; ++r)
                        Cf[(size_t)(grow + r)*N + gcol] = acc[i][j][r] + bv;
                }
            }
        }
    }

    if (stats){
        #pragma unroll
        for (int j = 0; j < 4; ++j){
            int gcol = n0 + wn + j*16 + fr;
            float bv = bias ? bias[gcol] : 0.f;
            float sv = 0.f, sq = 0.f;
            #pragma unroll
            for (int i = 0; i < 4; ++i)
                #pragma unroll
                for (int r = 0; r < 4; ++r){
                    float v = acc[i][j][r] + bv;
                    sv += v; sq += v*v;
                }
            sv += __shfl_xor(sv, 16, 64);  sq += __shfl_xor(sq, 16, 64);
            sv += __shfl_xor(sv, 32, 64);  sq += __shfl_xor(sq, 32, 64);
            if (lane < 16){
                atomicAdd(&stats[gcol], sv);
                atomicAdd(&stats[N + gcol], sq);
            }
        }
    }
}

// ---------- MFMA GEMM 128x64 tile (proj / pw2) ----------
// Both output paths LDS-staged coalesced bf16; scat path remaps rows only.
__global__ __launch_bounds__(256) void gemm_bt64(const ushort_t* __restrict__ A,
                                                 const ushort_t* __restrict__ B,
                                                 ushort_t* __restrict__ Cb,
                                                 float* __restrict__ Cf,
                                                 int M, int N, int K,
                                                 const float* __restrict__ bias,
                                                 float* __restrict__ stats,
                                                 int scat){
    const int nx   = gridDim.x;
    int flat = blockIdx.y * nx + blockIdx.x;
    int xcd  = flat & 7;
    int k    = flat >> 3;
    int by   = xcd + 8 * (k / nx);
    int bx   = k % nx;
    if (by * 128 >= M) return;

    __shared__ __align__(16) ushort_t As[2][128*32];
    __shared__ __align__(16) ushort_t Bs[2][64*32];
    const int tid  = threadIdx.x;
    const int lane = tid & 63;
    const int wid  = tid >> 6;
    const int m0 = by * 128;
    const int n0 = bx * 64;
    const int wm = (wid >> 1) * 64;
    const int wn = (wid & 1) * 32;

    const int srow = (lane >> 2);
    const int scol = (((lane & 3) ^ ((lane >> 3) & 3)) * 8);

    floatx4 acc[4][2] = {};

    auto stage = [&](int buf, int k0){
        #pragma unroll
        for (int j = 0; j < 2; ++j){
            int ch = wid*2 + j;
            const ushort_t* gA = A + (size_t)(m0 + ch*16 + srow)*K + k0 + scol;
            __builtin_amdgcn_global_load_lds(
                (const __attribute__((address_space(1))) void*)gA,
                (__attribute__((address_space(3))) void*)(&As[buf][ch*512 + lane*8]), 16, 0, 0);
        }
        const ushort_t* gB = B + (size_t)(n0 + wid*16 + srow)*K + k0 + scol;
        __builtin_amdgcn_global_load_lds(
            (const __attribute__((address_space(1))) void*)gB,
            (__attribute__((address_space(3))) void*)(&Bs[buf][wid*512 + lane*8]), 16, 0, 0);
    };

    const int NK = K >> 5;
    stage(0, 0);

    const int fr   = lane & 15;
    const int quad = lane >> 4;
    const int cosw = (quad ^ ((fr >> 1) & 3)) * 8;
    int cur = 0;
    for (int it = 0; it < NK; ++it){
        __builtin_amdgcn_sched_barrier(0);
        __builtin_amdgcn_s_barrier();
        if (it + 1 < NK){
            stage(cur ^ 1, (it + 1) << 5);
            asm volatile("s_waitcnt vmcnt(3)" ::: "memory");
        } else {
            asm volatile("s_waitcnt vmcnt(0)" ::: "memory");
        }
        __builtin_amdgcn_s_barrier();
        __builtin_amdgcn_sched_barrier(0);

        short8 af[4], bfr[2];
        #pragma unroll
        for (int i = 0; i < 4; ++i)
            af[i]  = *(const short8*)(&As[cur][(wm + i*16 + fr)*32 + cosw]);
        #pragma unroll
        for (int j = 0; j < 2; ++j)
            bfr[j] = *(const short8*)(&Bs[cur][(wn + j*16 + fr)*32 + cosw]);
        #pragma unroll
        for (int i = 0; i < 4; ++i)
            #pragma unroll
            for (int j = 0; j < 2; ++j)
                acc[i][j] = __builtin_amdgcn_mfma_f32_16x16x32_bf16(af[i], bfr[j], acc[i][j], 0, 0, 0);
        cur ^= 1;
    }

    if (Cb){
        __syncthreads();
        ushort_t* Cst = &As[0][0];
        #pragma unroll
        for (int i = 0; i < 4; ++i){
            #pragma unroll
            for (int j = 0; j < 2; ++j){
                int col = wn + j*16 + fr;
                float bv = bias ? bias[n0 + col] : 0.f;
                #pragma unroll
                for (int r = 0; r < 4; ++r)
                    Cst[(wm + i*16 + quad*4 + r)*64 + (col ^ (quad << 4))] =
                        f2b(acc[i][j][r] + bv);
            }
        }
        __syncthreads();
        #pragma unroll
        for (int q = 0; q < 4; ++q){
            int fl  = q*256 + tid;               // 1024 uint4s = 128 rows x 8
            int row = fl >> 3, u4c = fl & 7;
            int g = (row >> 2) & 3;
            int orow = scat ? scatter_row(m0 + row) : (m0 + row);
            *(uint4*)(Cb + (size_t)orow*N + n0 + u4c*8) =
                *(const uint4*)(Cst + row*64 + ((u4c*8) ^ (g << 4)));
        }
    } else {
        #pragma unroll
        for (int i = 0; i < 4; ++i){
            int grow = m0 + wm + i*16 + quad*4;
            #pragma unroll
            for (int j = 0; j < 2; ++j){
                int gcol = n0 + wn + j*16 + fr;
                float bv = bias ? bias[gcol] : 0.f;
                #pragma unroll
                for (int r = 0; r < 4; ++r)
                    Cf[(size_t)(grow + r)*N + gcol] = acc[i][j][r] + bv;
            }
        }
    }

    if (stats){
        #pragma unroll
        for (int j = 0; j < 2; ++j){
            int gcol = n0 + wn + j*16 + fr;
            float bv = bias ? bias[gcol] : 0.f;
            float sv = 0.f, sq = 0.f;
            #pragma unroll
            for (int i = 0; i < 4; ++i)
                #pragma unroll
                for (int r = 0; r < 4; ++r){
                    float v = acc[i][j][r] + bv;
                    sv += v; sq += v*v;
                }
            sv += __shfl_xor(sv, 16, 64);  sq += __shfl_xor(sq, 16, 64);
            sv += __shfl_xor(sv, 32, 64);  sq += __shfl_xor(sq, 32, 64);
            if (lane < 16){
                atomicAdd(&stats[gcol], sv);
                atomicAdd(&stats[N + gcol], sq);
            }
        }
    }
}

// ---------- MFMA attention (LDS-staged coalesced output) ----------
__global__ __launch_bounds__(256) void attn_mfma(const ushort_t* __restrict__ qkv,
                                                 ushort_t* __restrict__ outp,
                                                 const float* __restrict__ bm){
    __shared__ __align__(16) ushort_t Ps[64*72];
    __shared__ __align__(16) ushort_t VT[64*72];
    const int tid = threadIdx.x, lane = tid & 63, wid = tid >> 6;
    const int h = blockIdx.x, w = blockIdx.y, wi = w & 3;
    const int fr = lane & 15, quad = lane >> 4, co = quad*8;

    for (int idx = tid; idx < 64*8; idx += 256){
        int k = idx >> 3, ng = idx & 7;
        uint4 u = {0u, 0u, 0u, 0u};
        if (k < 49) u = *(const uint4*)(qkv + (size_t)(w*49 + k)*QKV3 + 1536 + h*64 + ng*8);
        const ushort_t* vp = (const ushort_t*)&u;
        #pragma unroll
        for (int e = 0; e < 8; ++e) VT[(ng*8 + e)*72 + k] = vp[e];
    }
    __syncthreads();

    floatx4 accs[4] = {};
    const ushort_t* qbase = qkv + (size_t)(w*49 + wid*16 + fr)*QKV3 + h*64;
    #pragma unroll
    for (int k0 = 0; k0 < 64; k0 += 32){
        short8 af = *(const short8*)(qbase + k0 + co);
        #pragma unroll
        for (int j = 0; j < 4; ++j){
            const ushort_t* kbase = qkv + (size_t)(w*49 + j*16 + fr)*QKV3 + 768 + h*64;
            short8 bf = *(const short8*)(kbase + k0 + co);
            accs[j] = __builtin_amdgcn_mfma_f32_16x16x32_bf16(af, bf, accs[j], 0, 0, 0);
        }
    }

    const float* bmh = bm + (size_t)((h*4 + wi)*64 + wid*16)*64;
    #pragma unroll
    for (int r = 0; r < 4; ++r){
        int lrow = quad*4 + r;
        float m = -3e38f;
        #pragma unroll
        for (int j = 0; j < 4; ++j){
            float a = accs[j][r]*0.125f + bmh[lrow*64 + j*16 + fr];
            accs[j][r] = a;
            m = fmaxf(m, a);
        }
        #pragma unroll
        for (int off = 1; off < 16; off <<= 1) m = fmaxf(m, __shfl_xor(m, off, 64));
        float s = 0.f;
        #pragma unroll
        for (int j = 0; j < 4; ++j){
            float e = __expf(accs[j][r] - m);
            accs[j][r] = e; s += e;
        }
        #pragma unroll
        for (int off = 1; off < 16; off <<= 1) s += __shfl_xor(s, off, 64);
        float inv = 1.f / s;
        #pragma unroll
        for (int j = 0; j < 4; ++j)
            Ps[(wid*16 + lrow)*72 + j*16 + fr] = f2b(accs[j][r]*inv);
    }
    __syncthreads();

    floatx4 acco[4] = {};
    #pragma unroll
    for (int k0 = 0; k0 < 64; k0 += 32){
        short8 af = *(const short8*)(Ps + (wid*16 + fr)*72 + k0 + co);
        #pragma unroll
        for (int j = 0; j < 4; ++j){
            short8 bf = *(const short8*)(VT + (j*16 + fr)*72 + k0 + co);
            acco[j] = __builtin_amdgcn_mfma_f32_16x16x32_bf16(af, bf, acco[j], 0, 0, 0);
        }
    }
    // stage O tile into Ps (dead after PV), then coalesced 16B stores
    __syncthreads();
    #pragma unroll
    for (int r = 0; r < 4; ++r){
        int orow = wid*16 + quad*4 + r;
        #pragma unroll
        for (int j = 0; j < 4; ++j)
            Ps[orow*72 + j*16 + fr] = f2b(acco[j][r]);
    }
    __syncthreads();
    for (int it = tid; it < 49*8; it += 256){
        int row = it >> 3, u4c = it & 7;
        *(uint4*)(outp + (size_t)(w*49 + row)*CDIM + h*64 + u4c*8) =
            *(const uint4*)(Ps + row*72 + u4c*8);
    }
}

// ---------- depthwise 3x3 + bn1(folded)+hswish + FUSED bn2-stats ----------
__global__ __launch_bounds__(256) void dwconv_s(const ushort_t* __restrict__ in,
                                                const float* __restrict__ wT,
                                                const float* __restrict__ sums1,
                                                const float* __restrict__ g1,
                                                const float* __restrict__ b1,
                                                ushort_t* __restrict__ out,
                                                float* __restrict__ sums2){
    const int cgl = threadIdx.x & 31;
    const int rp  = threadIdx.x >> 5;
    const int cg  = blockIdx.x*32 + cgl;       // [0,384)
    const int c   = cg*8;
    const int r0  = blockIdx.y*112;
    float sc[8], sh[8];
    #pragma unroll
    for (int e = 0; e < 8; ++e) bn_coef(sums1, HID, g1, b1, c+e, sc[e], sh[e]);
    float wv[9][8];
    #pragma unroll
    for (int kk = 0; kk < 9; ++kk){
        const float4* wp = (const float4*)(wT + kk*HID + c);
        float4 w0 = wp[0], w1 = wp[1];
        wv[kk][0]=w0.x; wv[kk][1]=w0.y; wv[kk][2]=w0.z; wv[kk][3]=w0.w;
        wv[kk][4]=w1.x; wv[kk][5]=w1.y; wv[kk][6]=w1.z; wv[kk][7]=w1.w;
    }
    float s[8] = {}, q[8] = {};
    for (int r = r0 + rp; r < r0 + 112; r += 8){
        int b = r / 196, p = r % 196;
        int y = p / 14,  x = p % 14;
        const uint4* inb = (const uint4*)(in + (size_t)b*196*HID);
        float acc[8] = {};
        #pragma unroll
        for (int ky = 0; ky < 3; ++ky){
            int yy = y + ky - 1;
            if ((unsigned)yy >= 14u) continue;
            #pragma unroll
            for (int kx = 0; kx < 3; ++kx){
                int xx = x + kx - 1;
                if ((unsigned)xx >= 14u) continue;
                uint4 u = inb[(yy*14 + xx)*384 + cg];
                float fin[8]; unpack8(u, fin);
                #pragma unroll
                for (int e = 0; e < 8; ++e)
                    acc[e] += hswish(fin[e]*sc[e] + sh[e]) * wv[ky*3 + kx][e];
            }
        }
        ((uint4*)out)[(size_t)r*384 + cg] = pack8(acc);
        #pragma unroll
        for (int e = 0; e < 8; ++e){ s[e] += acc[e]; q[e] += acc[e]*acc[e]; }
    }
    #pragma unroll
    for (int e = 0; e < 8; ++e){
        s[e] += __shfl_xor(s[e], 32, 64);
        q[e] += __shfl_xor(q[e], 32, 64);
    }
    __shared__ float red[4][32][17];
    const int wvv = threadIdx.x >> 6;
    if ((threadIdx.x & 32) == 0){
        #pragma unroll
        for (int e = 0; e < 8; ++e){
            red[wvv][cgl][e]   = s[e];
            red[wvv][cgl][8+e] = q[e];
        }
    }
    __syncthreads();
    #pragma unroll
    for (int k = 0; k < 2; ++k){
        int o = threadIdx.x*2 + k;
        int cgo = o >> 4, e = o & 15;
        float v = red[0][cgo][e] + red[1][cgo][e] + red[2][cgo][e] + red[3][cgo][e];
        int cc = blockIdx.x*256 + cgo*8 + (e & 7);
        atomicAdd(&sums2[(e < 8 ? 0 : HID) + cc], v);
    }
}

// ---------- SE (bn2 folded on read) ----------
__global__ __launch_bounds__(256) void se_mean_v(const ushort_t* __restrict__ X,
                                                 const float* __restrict__ sums2,
                                                 const float* __restrict__ g2,
                                                 const float* __restrict__ b2,
                                                 float* __restrict__ s){
    const int b   = blockIdx.x;
    const int cgl = threadIdx.x & 31;
    const int rp  = threadIdx.x >> 5;
    const int cg  = blockIdx.y*32 + cgl;
    const int c   = cg*8;
    float sc[8], sh[8];
    #pragma unroll
    for (int e = 0; e < 8; ++e) bn_coef(sums2, HID, g2, b2, c+e, sc[e], sh[e]);
    const uint4* Xb = (const uint4*)(X + (size_t)b*196*HID);
    float a[8] = {};
    for (int p = rp; p < 196; p += 8){
        uint4 u = Xb[(size_t)p*384 + cg];
        float f[8]; unpack8(u, f);
        #pragma unroll
        for (int e = 0; e < 8; ++e) a[e] += hswish(f[e]*sc[e] + sh[e]);
    }
    #pragma unroll
    for (int e = 0; e < 8; ++e) a[e] += __shfl_xor(a[e], 32, 64);
    __shared__ float red[4][32][9];
    const int wv = threadIdx.x >> 6;
    if ((threadIdx.x & 32) == 0){
        #pragma unroll
        for (int e = 0; e < 8; ++e) red[wv][cgl][e] = a[e];
    }
    __syncthreads();
    {
        int o = threadIdx.x;
        int cgo = o >> 3, e = o & 7;
        float v = red[0][cgo][e] + red[1][cgo][e] + red[2][cgo][e] + red[3][cgo][e];
        s[(size_t)b*HID + blockIdx.y*256 + cgo*8 + e] = v * (1.f/196.f);
    }
}
__global__ __launch_bounds__(256) void se_fc(const float* __restrict__ in,
                                             const float* __restrict__ w,
                                             const float* __restrict__ bias,
                                             float* __restrict__ out,
                                             int IN, int OUT, int mode){
    int wv   = (blockIdx.x*256 + threadIdx.x) >> 6;
    int lane = threadIdx.x & 63;
    if (wv >= OUT) return;
    const float* wr = w + (size_t)wv * IN;
    float acc[32];
    #pragma unroll
    for (int b = 0; b < 32; ++b) acc[b] = 0.f;
    for (int k = lane; k < IN; k += 64){
        float wval = wr[k];
        #pragma unroll
        for (int b = 0; b < 32; ++b)
            acc[b] += in[b*IN + k] * wval;
    }
    #pragma unroll
    for (int b = 0; b < 32; ++b){
        float v = acc[b];
        #pragma unroll
        for (int off = 32; off; off >>= 1) v += __shfl_down(v, off, 64);
        if (lane == 0){
            float a = v + bias[wv];
            if (mode == 0) a = fmaxf(a, 0.f);
            else           a = fminf(fmaxf(a + 3.f, 0.f), 6.f) * (1.f/6.f);
            out[b*OUT + wv] = a;
        }
    }
}
__global__ __launch_bounds__(256) void se_scale(ushort_t* __restrict__ X,
                                                const float* __restrict__ sums2,
                                                const float* __restrict__ g2,
                                                const float* __restrict__ b2,
                                                const float* __restrict__ s2){
    int idx = blockIdx.x*256 + threadIdx.x;
    if (idx >= MROWS * (HID/8)) return;
    int r = idx / (HID/8), c8 = idx % (HID/8);
    int b = r / 196;
    int c = c8*8;
    uint4 u = ((uint4*)X)[idx];
    float f[8]; unpack8(u, f);
    const float* sp = s2 + b*HID + c;
    #pragma unroll
    for (int e = 0; e < 8; ++e){
        float sc, sh;
        bn_coef(sums2, HID, g2, b2, c+e, sc, sh);
        f[e] = hswish(f[e]*sc + sh) * sp[e];
    }
    ((uint4*)X)[idx] = pack8(f);
}

// ---------- final: out = [cls | f_bf16 + h_bf16*sc + sh], bn3 folded ----------
__global__ __launch_bounds__(256) void final_k(const float4* __restrict__ xin,
                                               const ushort_t* __restrict__ fb,
                                               const ushort_t* __restrict__ hb4,
                                               const float* __restrict__ sums3,
                                               const float* __restrict__ g3,
                                               const float* __restrict__ b3,
                                               float4* __restrict__ outp){
    int idx = blockIdx.x*256 + threadIdx.x;        // over 32*197*96 (8-elem groups)
    if (idx >= 32*197*96) return;
    int b = idx / (197*96);
    int rem = idx % (197*96);
    int n = rem / 96, c8 = rem % 96;
    size_t obase = ((size_t)b*197 + n)*192 + c8*2;
    if (n == 0){
        outp[obase]     = xin[obase];
        outp[obase + 1] = xin[obase + 1];
        return;
    }
    size_t off = ((size_t)b*196 + n - 1)*96 + c8;
    uint4 fu = ((const uint4*)fb)[off];
    uint4 hu = ((const uint4*)hb4)[off];
    float fv[8], hv[8];
    unpack8(fu, fv); unpack8(hu, hv);
    int c = c8*8;
    float o[8];
    #pragma unroll
    for (int e = 0; e < 8; ++e){
        float sc, sh;
        bn_coef(sums3, CDIM, g3, b3, c+e, sc, sh);
        o[e] = fv[e] + hv[e]*sc + sh;
    }
    float4 o0 = {o[0], o[1], o[2], o[3]};
    float4 o1 = {o[4], o[5], o[6], o[7]};
    outp[obase]     = o0;
    outp[obase + 1] = o1;
}

extern "C" void kernel_launch(void* const* d_in, const int* in_sizes, int n_in,
                              void* d_out, int out_size, void* d_ws, size_t ws_size,
                              hipStream_t stream){
    const float* x      = (const float*)d_in[0];
    const float* w_qkv  = (const float*)d_in[1];
    const float* w_proj = (const float*)d_in[2];
    const float* b_proj = (const float*)d_in[3];
    const float* rpb    = (const float*)d_in[4];
    const float* pw1_w  = (const float*)d_in[5];
    const float* bn1_g  = (const float*)d_in[6];
    const float* bn1_b  = (const float*)d_in[7];
    const float* dw_w   = (const float*)d_in[8];
    const float* bn2_g  = (const float*)d_in[9];
    const float* bn2_b  = (const float*)d_in[10];
    const float* se_w1  = (const float*)d_in[11];
    const float* se_b1  = (const float*)d_in[12];
    const float* se_w2  = (const float*)d_in[13];
    const float* se_b2  = (const float*)d_in[14];
    const float* pw2_w  = (const float*)d_in[15];
    const float* bn3_g  = (const float*)d_in[16];
    const float* bn3_b  = (const float*)d_in[17];

    char* ws = (char*)d_ws;
    // Lifetime map (verified r11):
    //  [0, 9.63M):        win (prep) -> dead after qkv gemm -> hb (dwconv out)
    //  [9.63M, 38.54M):   qkv (qkv gemm -> attn)
    //  [38.54M, 48.17M):  wqkvb (prep) -> attnb (attn out) -> ha (pw1 out) -> hb4 (pw2 out)
    //  [48.17M, 49.35M):  wprojb (prep -> proj)
    //  [49.35M, 50.13M):  bm (prep -> attn; clobbered later by ha)
    //  [50.13M, 77.07M):  ha tail (pw1 out spans [38.54M, 77.07M))
    //  [77.07M, 86.70M):  fb2 (proj out; lives to final_k)
    //  [86.70M, 86.73M):  sums2 | sums3 (contiguous, zeroed in prep)
    //  [86.73M, 91.45M):  pw1b (prep -> pw1 gemm; untouched in between)
    //  [91.45M, 96.17M):  pw2b (prep -> pw2 gemm; untouched in between)
    //  [96.34M, ...):     sums1 | s | s1 | s2/dwwT
    ushort_t* win    = (ushort_t*)(ws + 0);
    ushort_t* hb     = (ushort_t*)(ws + 0);
    ushort_t* qkv    = (ushort_t*)(ws + 9633792);
    ushort_t* wqkvb  = (ushort_t*)(ws + 38535168);
    ushort_t* attnb  = (ushort_t*)(ws + 38535168);
    ushort_t* ha     = (ushort_t*)(ws + 38535168);
    ushort_t* hb4    = (ushort_t*)(ws + 38535168);
    ushort_t* wprojb = (ushort_t*)(ws + 48168960);
    float*    bm     = (float*)(ws + 49348608);
    ushort_t* fb2    = (ushort_t*)(ws + 77070336);
    float*    sums2  = (float*)(ws + 86704128);
    float*    sums3  = (float*)(ws + 86728704);
    ushort_t* pw1b   = (ushort_t*)(ws + 86734848);
    ushort_t* pw2b   = (ushort_t*)(ws + 91453440);
    float*    sums1  = (float*)(ws + 96337920);
    float*    s      = (float*)(ws + 96362496);
    float*    s1     = (float*)(ws + 96755712);
    float*    s2     = (float*)(ws + 96854016);
    float*    dwwT   = (float*)(ws + 96854016);    // alias s2: dead before se_fc writes s2

    const int vec_hid8 = (MROWS*(HID/8) + 255)/256;
    const int GY = 56;

    // single fused prep: zeros + dwT + 4 weight casts + window gather + bias/mask table
    prep_k<<<12546, 256, 0, stream>>>((const float4*)x, (const float4*)w_qkv,
                                      (const float4*)w_proj, (const float4*)pw1_w,
                                      (const float4*)pw2_w, dw_w, rpb,
                                      sums1, sums2, dwwT,
                                      (ushort4*)wqkvb, (ushort4*)wprojb,
                                      (ushort4*)pw1b, (ushort4*)pw2b,
                                      (ushort4*)win, bm);

    // attention half
    gemm_bt<<<dim3(QKV3/128, GY), 256, 0, stream>>>(win, wqkvb, qkv, nullptr, MROWS, QKV3, CDIM, nullptr, nullptr, 0);
    attn_mfma<<<dim3(12, 128), 256, 0, stream>>>(qkv, attnb, bm);
    gemm_bt64<<<dim3(CDIM/64, GY), 256, 0, stream>>>(attnb, wprojb, fb2, nullptr, MROWS, CDIM, CDIM, b_proj, nullptr, 1);

    // ConvFFN half
    gemm_bt<<<dim3(HID/128, GY), 256, 0, stream>>>(fb2, pw1b, ha, nullptr, MROWS, HID, CDIM, nullptr, sums1, 0);
    dwconv_s<<<dim3(12, GY), 256, 0, stream>>>(ha, dwwT, sums1, bn1_g, bn1_b, hb, sums2);   // bn1 folded + bn2-stats
    se_mean_v<<<dim3(32, 12), 256, 0, stream>>>(hb, sums2, bn2_g, bn2_b, s);                // bn2 folded
    se_fc<<<dim3((CDIM*64)/256), 256, 0, stream>>>(s, se_w1, se_b1, s1, HID, CDIM, 0);
    se_fc<<<dim3((HID*64)/256), 256, 0, stream>>>(s1, se_w2, se_b2, s2, CDIM, HID, 1);
    se_scale<<<vec_hid8, 256, 0, stream>>>(hb, sums2, bn2_g, bn2_b, s2);                    // bn2 folded

    gemm_bt64<<<dim3(CDIM/64, GY), 256, 0, stream>>>(hb, pw2b, hb4, nullptr, MROWS, CDIM, HID, nullptr, sums3, 0);
    final_k<<<(32*197*96 + 255)/256, 256, 0, stream>>>((const float4*)x, fb2, hb4, sums3, bn3_g, bn3_b, (float4*)d_out);
}

// Round 13
// 494.896 us; speedup vs baseline: 1.1378x; 1.0037x over previous
//
#include <hip/hip_runtime.h>
#include <hip/hip_bf16.h>

typedef unsigned short ushort_t;
typedef unsigned int uint_t;
typedef short short8 __attribute__((ext_vector_type(8)));
typedef float floatx4 __attribute__((ext_vector_type(4)));

// ---------- bf16 helpers (raw ushort storage) ----------
__device__ inline float b2f(ushort_t u){
    uint_t v = ((uint_t)u) << 16;
    return __uint_as_float(v);
}
__device__ inline ushort_t f2b(float f){
    uint_t v = __float_as_uint(f);
    uint_t r = (v + 0x7FFFu + ((v >> 16) & 1u)) >> 16;  // RNE
    return (ushort_t)r;
}
__device__ inline void unpack8(uint4 u, float* f){
    uint_t w[4] = {u.x, u.y, u.z, u.w};
    #pragma unroll
    for (int i = 0; i < 4; ++i){
        f[2*i]   = __uint_as_float(w[i] << 16);
        f[2*i+1] = __uint_as_float(w[i] & 0xFFFF0000u);
    }
}
__device__ inline uint4 pack8(const float* f){
    uint4 o;
    uint_t w[4];
    #pragma unroll
    for (int i = 0; i < 4; ++i)
        w[i] = (uint_t)f2b(f[2*i]) | ((uint_t)f2b(f[2*i+1]) << 16);
    o.x = w[0]; o.y = w[1]; o.z = w[2]; o.w = w[3];
    return o;
}
__device__ inline ushort4 cvt4(float4 v){
    ushort4 o;
    o.x = f2b(v.x); o.y = f2b(v.y); o.z = f2b(v.z); o.w = f2b(v.w);
    return o;
}
__device__ inline float hswish(float y){
    return y * fminf(fmaxf(y + 3.f, 0.f), 6.f) * (1.f/6.f);
}

// ---------- constants ----------
#define MROWS 6272
#define CDIM  768
#define HID   3072
#define QKV3  2304

// swin window->spatial row map (with +3 roll): ri (window layout) -> dest row (b*196+p)
__device__ inline int scatter_row(int ri){
    int w  = ri / 49, t = ri % 49;
    int b  = w >> 2,  wi = w & 3;
    int wy = wi >> 1, wx = wi & 1;
    int ty = t / 7,   tx = t % 7;
    int yd = (wy*7 + ty + 3) % 14;
    int xd = (wx*7 + tx + 3) % 14;
    return b*196 + yd*14 + xd;
}

// bn scale/shift from raw sums (folded bn_finalize)
__device__ inline void bn_coef(const float* __restrict__ sums, int Cch,
                               const float* __restrict__ g, const float* __restrict__ b,
                               int c, float& sc, float& sh){
    float mean = sums[c] * (1.f/6272.f);
    float var  = sums[Cch + c] * (1.f/6272.f) - mean*mean;
    float s = g[c] * rsqrtf(var + 1e-5f);
    sc = s;
    sh = b[c] - mean*s;
}

// ---------- fused prep: zeros + dw transpose + 4 weight casts + gather + bias/mask ----------
// Block ranges (each job guarded): 24|30|108|1728|576|2304|2304|4704|768 = 12546 blocks.
__global__ __launch_bounds__(256) void prep_k(const float4* __restrict__ x,
                                              const float4* __restrict__ w_qkv,
                                              const float4* __restrict__ w_proj,
                                              const float4* __restrict__ pw1_w,
                                              const float4* __restrict__ pw2_w,
                                              const float* __restrict__ dw_w,
                                              const float* __restrict__ rpb,
                                              float* __restrict__ sums1,
                                              float* __restrict__ sums23,
                                              float* __restrict__ dwwT,
                                              ushort4* __restrict__ wqkvb,
                                              ushort4* __restrict__ wprojb,
                                              ushort4* __restrict__ pw1b,
                                              ushort4* __restrict__ pw2b,
                                              ushort4* __restrict__ win,
                                              float* __restrict__ bm){
    int bid = blockIdx.x;
    const int t = threadIdx.x;
    if (bid < 24){ int i = bid*256 + t; if (i < 2*HID) sums1[i] = 0.f; return; }
    bid -= 24;
    if (bid < 30){ int i = bid*256 + t; if (i < 2*HID + 2*CDIM) sums23[i] = 0.f; return; }
    bid -= 30;
    if (bid < 108){
        int i = bid*256 + t;
        if (i < HID*9){ int c = i/9, k = i%9; dwwT[k*HID + c] = dw_w[i]; }
        return;
    }
    bid -= 108;
    if (bid < 1728){ int i = bid*256 + t; wqkvb[i] = cvt4(w_qkv[i]); return; }   // 442368 exact
    bid -= 1728;
    if (bid < 576){ int i = bid*256 + t; wprojb[i] = cvt4(w_proj[i]); return; }  // 147456 exact
    bid -= 576;
    if (bid < 2304){ int i = bid*256 + t; pw1b[i] = cvt4(pw1_w[i]); return; }    // 589824 exact
    bid -= 2304;
    if (bid < 2304){ int i = bid*256 + t; pw2b[i] = cvt4(pw2_w[i]); return; }
    bid -= 2304;
    if (bid < 4704){                                                              // gather: 1204224 exact
        int idx = bid*256 + t;
        int r  = idx / 192, c4 = idx % 192;
        int w  = r / 49,  tt = r % 49;
        int b  = w >> 2,  wi = w & 3;
        int wy = wi >> 1, wx = wi & 1;
        int ty = tt / 7,  tx = tt % 7;
        int ys = (wy*7 + ty + 3) % 14;
        int xs = (wx*7 + tx + 3) % 14;
        win[idx] = cvt4(x[(size_t)b*197*192 + (size_t)(1 + ys*14 + xs)*192 + c4]);
        return;
    }
    bid -= 4704;
    {                                                                             // bm: 196608 exact
        int idx = bid*256 + t;
        int ki = idx & 63, qi = (idx >> 6) & 63, wi = (idx >> 12) & 3, h = idx >> 14;
        float v = -1e30f;
        if (qi < 49 && ki < 49){
            int qy = qi/7, qx = qi%7, ky = ki/7, kx = ki%7;
            int ridx = (qy - ky + 6)*13 + (qx - kx + 6);
            v = rpb[ridx*12 + h];
            int wy = wi >> 1, wx = wi & 1;
            int gqy = wy*7 + qy, gqx = wx*7 + qx, gky = wy*7 + ky, gkx = wx*7 + kx;
            int cq = ((gqy < 7) ? 0 : (gqy < 11 ? 1 : 2))*3 + ((gqx < 7) ? 0 : (gqx < 11 ? 1 : 2));
            int ck = ((gky < 7) ? 0 : (gky < 11 ? 1 : 2))*3 + ((gkx < 7) ? 0 : (gkx < 11 ? 1 : 2));
            if (cq != ck) v -= 100.f;
        }
        bm[idx] = v;
    }
}

// ---------- MFMA GEMM 256x128 tile, BK=32, 8 waves (qkv / pw1) ----------
// Same verified stage/swizzle/2-barrier counted-vmcnt machinery as the 128-tile
// kernel; 2x M-tile halves A re-fetch traffic. LDS 48KB -> up to 3 blocks/CU.
// Epilogue: two-pass LDS-staged coalesced bf16 store (C rows 0-127, then 128-255).
__global__ __launch_bounds__(512) void gemm256_32(const ushort_t* __restrict__ A,
                                                  const ushort_t* __restrict__ B,
                                                  ushort_t* __restrict__ Cb,
                                                  int M, int N, int K,
                                                  float* __restrict__ stats){
    const int nx   = gridDim.x;
    int flat = blockIdx.y * nx + blockIdx.x;
    int xcd  = flat & 7;
    int k    = flat >> 3;
    int by   = xcd + 8 * (k / nx);
    int bx   = k % nx;
    if (by * 256 >= M) return;

    __shared__ __align__(16) ushort_t As[2][256*32];
    __shared__ __align__(16) ushort_t Bs[2][128*32];
    const int tid  = threadIdx.x;
    const int lane = tid & 63;
    const int wid  = tid >> 6;            // 8 waves: 4 M-quadrants x 2 N-halves
    const int m0 = by * 256;
    const int n0 = bx * 128;
    const int wm = (wid >> 1) * 64;
    const int wn = (wid & 1) * 64;

    const int srow = (lane >> 2);
    const int scol = (((lane & 3) ^ ((lane >> 3) & 3)) * 8);

    floatx4 acc[4][4] = {};

    auto stage = [&](int buf, int k0){        // 3 global_load_lds per thread
        #pragma unroll
        for (int j = 0; j < 2; ++j){
            int ch  = wid*2 + j;              // A chunks 0..15 (16-row each)
            int row = m0 + ch*16 + srow;
            if (row > M-1) row = M-1;         // M-tail clamp (writes guarded)
            const ushort_t* gA = A + (size_t)row*K + k0 + scol;
            __builtin_amdgcn_global_load_lds(
                (const __attribute__((address_space(1))) void*)gA,
                (__attribute__((address_space(3))) void*)(&As[buf][ch*512 + lane*8]), 16, 0, 0);
        }
        const ushort_t* gB = B + (size_t)(n0 + wid*16 + srow)*K + k0 + scol;
        __builtin_amdgcn_global_load_lds(
            (const __attribute__((address_space(1))) void*)gB,
            (__attribute__((address_space(3))) void*)(&Bs[buf][wid*512 + lane*8]), 16, 0, 0);
    };

    const int NK = K >> 5;
    stage(0, 0);

    const int fr   = lane & 15;
    const int quad = lane >> 4;
    const int cosw = (quad ^ ((fr >> 1) & 3)) * 8;
    int cur = 0;
    for (int it = 0; it < NK; ++it){
        __builtin_amdgcn_sched_barrier(0);
        __builtin_amdgcn_s_barrier();         // barrier_a: prev iter's LDS reads done
        if (it + 1 < NK){
            stage(cur ^ 1, (it + 1) << 5);
            asm volatile("s_waitcnt vmcnt(3)" ::: "memory");
        } else {
            asm volatile("s_waitcnt vmcnt(0)" ::: "memory");
        }
        __builtin_amdgcn_s_barrier();         // barrier_b: everyone's stage(it) landed
        __builtin_amdgcn_sched_barrier(0);

        short8 af[4], bfr[4];
        #pragma unroll
        for (int i = 0; i < 4; ++i){
            af[i]  = *(const short8*)(&As[cur][(wm + i*16 + fr)*32 + cosw]);
            bfr[i] = *(const short8*)(&Bs[cur][(wn + i*16 + fr)*32 + cosw]);
        }
        #pragma unroll
        for (int i = 0; i < 4; ++i)
            #pragma unroll
            for (int j = 0; j < 4; ++j)
                acc[i][j] = __builtin_amdgcn_mfma_f32_16x16x32_bf16(af[i], bfr[j], acc[i][j], 0, 0, 0);
        cur ^= 1;
    }

    // ---- two-pass LDS-staged coalesced bf16 store (Cs = 128x128 over As) ----
    __syncthreads();
    ushort_t* Cs = &As[0][0];                 // 16384 ushorts = 128 x 128
    #pragma unroll
    for (int p = 0; p < 2; ++p){
        if ((wid >> 2) == p){                 // waves owning rows p*128 .. p*128+127
            int lr0 = wm - p*128;             // 0 or 64
            #pragma unroll
            for (int i = 0; i < 4; ++i){
                #pragma unroll
                for (int j = 0; j < 4; ++j){
                    int col = wn + j*16 + fr;
                    #pragma unroll
                    for (int r = 0; r < 4; ++r)
                        Cs[(lr0 + i*16 + quad*4 + r)*128 + (col ^ (quad << 4))] =
                            f2b(acc[i][j][r]);
                }
            }
        }
        __syncthreads();
        #pragma unroll
        for (int q = 0; q < 4; ++q){
            int fl  = q*512 + tid;            // 2048 uint4s = 128 rows x 16
            int row = fl >> 4, u4c = fl & 15;
            int grow = m0 + p*128 + row;
            if (grow < M){
                int g = (row >> 2) & 3;
                *(uint4*)(Cb + (size_t)grow*N + n0 + u4c*8) =
                    *(const uint4*)(Cs + row*128 + ((u4c*8) ^ (g << 4)));
            }
        }
        __syncthreads();
    }

    if (stats){
        #pragma unroll
        for (int j = 0; j < 4; ++j){
            int gcol = n0 + wn + j*16 + fr;
            float sv = 0.f, sq = 0.f;
            #pragma unroll
            for (int i = 0; i < 4; ++i){
                int grow = m0 + wm + i*16 + quad*4;
                #pragma unroll
                for (int r = 0; r < 4; ++r){
                    if (grow + r < M){
                        float v = acc[i][j][r];
                        sv += v; sq += v*v;
                    }
                }
            }
            sv += __shfl_xor(sv, 16, 64);  sq += __shfl_xor(sq, 16, 64);
            sv += __shfl_xor(sv, 32, 64);  sq += __shfl_xor(sq, 32, 64);
            if (lane < 16){
                atomicAdd(&stats[gcol], sv);
                atomicAdd(&stats[N + gcol], sq);
            }
        }
    }
}

// ---------- MFMA GEMM 128x64 tile (proj / pw2) ----------
// Both output paths LDS-staged coalesced bf16; scat path remaps rows only.
__global__ __launch_bounds__(256) void gemm_bt64(const ushort_t* __restrict__ A,
                                                 const ushort_t* __restrict__ B,
                                                 ushort_t* __restrict__ Cb,
                                                 float* __restrict__ Cf,
                                                 int M, int N, int K,
                                                 const float* __restrict__ bias,
                                                 float* __restrict__ stats,
                                                 int scat){
    const int nx   = gridDim.x;
    int flat = blockIdx.y * nx + blockIdx.x;
    int xcd  = flat & 7;
    int k    = flat >> 3;
    int by   = xcd + 8 * (k / nx);
    int bx   = k % nx;
    if (by * 128 >= M) return;

    __shared__ __align__(16) ushort_t As[2][128*32];
    __shared__ __align__(16) ushort_t Bs[2][64*32];
    const int tid  = threadIdx.x;
    const int lane = tid & 63;
    const int wid  = tid >> 6;
    const int m0 = by * 128;
    const int n0 = bx * 64;
    const int wm = (wid >> 1) * 64;
    const int wn = (wid & 1) * 32;

    const int srow = (lane >> 2);
    const int scol = (((lane & 3) ^ ((lane >> 3) & 3)) * 8);

    floatx4 acc[4][2] = {};

    auto stage = [&](int buf, int k0){
        #pragma unroll
        for (int j = 0; j < 2; ++j){
            int ch = wid*2 + j;
            const ushort_t* gA = A + (size_t)(m0 + ch*16 + srow)*K + k0 + scol;
            __builtin_amdgcn_global_load_lds(
                (const __attribute__((address_space(1))) void*)gA,
                (__attribute__((address_space(3))) void*)(&As[buf][ch*512 + lane*8]), 16, 0, 0);
        }
        const ushort_t* gB = B + (size_t)(n0 + wid*16 + srow)*K + k0 + scol;
        __builtin_amdgcn_global_load_lds(
            (const __attribute__((address_space(1))) void*)gB,
            (__attribute__((address_space(3))) void*)(&Bs[buf][wid*512 + lane*8]), 16, 0, 0);
    };

    const int NK = K >> 5;
    stage(0, 0);

    const int fr   = lane & 15;
    const int quad = lane >> 4;
    const int cosw = (quad ^ ((fr >> 1) & 3)) * 8;
    int cur = 0;
    for (int it = 0; it < NK; ++it){
        __builtin_amdgcn_sched_barrier(0);
        __builtin_amdgcn_s_barrier();
        if (it + 1 < NK){
            stage(cur ^ 1, (it + 1) << 5);
            asm volatile("s_waitcnt vmcnt(3)" ::: "memory");
        } else {
            asm volatile("s_waitcnt vmcnt(0)" ::: "memory");
        }
        __builtin_amdgcn_s_barrier();
        __builtin_amdgcn_sched_barrier(0);

        short8 af[4], bfr[2];
        #pragma unroll
        for (int i = 0; i < 4; ++i)
            af[i]  = *(const short8*)(&As[cur][(wm + i*16 + fr)*32 + cosw]);
        #pragma unroll
        for (int j = 0; j < 2; ++j)
            bfr[j] = *(const short8*)(&Bs[cur][(wn + j*16 + fr)*32 + cosw]);
        #pragma unroll
        for (int i = 0; i < 4; ++i)
            #pragma unroll
            for (int j = 0; j < 2; ++j)
                acc[i][j] = __builtin_amdgcn_mfma_f32_16x16x32_bf16(af[i], bfr[j], acc[i][j], 0, 0, 0);
        cur ^= 1;
    }

    if (Cb){
        __syncthreads();
        ushort_t* Cst = &As[0][0];
        #pragma unroll
        for (int i = 0; i < 4; ++i){
            #pragma unroll
            for (int j = 0; j < 2; ++j){
                int col = wn + j*16 + fr;
                float bv = bias ? bias[n0 + col] : 0.f;
                #pragma unroll
                for (int r = 0; r < 4; ++r)
                    Cst[(wm + i*16 + quad*4 + r)*64 + (col ^ (quad << 4))] =
                        f2b(acc[i][j][r] + bv);
            }
        }
        __syncthreads();
        #pragma unroll
        for (int q = 0; q < 4; ++q){
            int fl  = q*256 + tid;               // 1024 uint4s = 128 rows x 8
            int row = fl >> 3, u4c = fl & 7;
            int g = (row >> 2) & 3;
            int orow = scat ? scatter_row(m0 + row) : (m0 + row);
            *(uint4*)(Cb + (size_t)orow*N + n0 + u4c*8) =
                *(const uint4*)(Cst + row*64 + ((u4c*8) ^ (g << 4)));
        }
    } else {
        #pragma unroll
        for (int i = 0; i < 4; ++i){
            int grow = m0 + wm + i*16 + quad*4;
            #pragma unroll
            for (int j = 0; j < 2; ++j){
                int gcol = n0 + wn + j*16 + fr;
                float bv = bias ? bias[gcol] : 0.f;
                #pragma unroll
                for (int r = 0; r < 4; ++r)
                    Cf[(size_t)(grow + r)*N + gcol] = acc[i][j][r] + bv;
            }
        }
    }

    if (stats){
        #pragma unroll
        for (int j = 0; j < 2; ++j){
            int gcol = n0 + wn + j*16 + fr;
            float bv = bias ? bias[gcol] : 0.f;
            float sv = 0.f, sq = 0.f;
            #pragma unroll
            for (int i = 0; i < 4; ++i)
                #pragma unroll
                for (int r = 0; r < 4; ++r){
                    float v = acc[i][j][r] + bv;
                    sv += v; sq += v*v;
                }
            sv += __shfl_xor(sv, 16, 64);  sq += __shfl_xor(sq, 16, 64);
            sv += __shfl_xor(sv, 32, 64);  sq += __shfl_xor(sq, 32, 64);
            if (lane < 16){
                atomicAdd(&stats[gcol], sv);
                atomicAdd(&stats[N + gcol], sq);
            }
        }
    }
}

// ---------- MFMA attention (LDS-staged coalesced output) ----------
__global__ __launch_bounds__(256) void attn_mfma(const ushort_t* __restrict__ qkv,
                                                 ushort_t* __restrict__ outp,
                                                 const float* __restrict__ bm){
    __shared__ __align__(16) ushort_t Ps[64*72];
    __shared__ __align__(16) ushort_t VT[64*72];
    const int tid = threadIdx.x, lane = tid & 63, wid = tid >> 6;
    const int h = blockIdx.x, w = blockIdx.y, wi = w & 3;
    const int fr = lane & 15, quad = lane >> 4, co = quad*8;

    for (int idx = tid; idx < 64*8; idx += 256){
        int k = idx >> 3, ng = idx & 7;
        uint4 u = {0u, 0u, 0u, 0u};
        if (k < 49) u = *(const uint4*)(qkv + (size_t)(w*49 + k)*QKV3 + 1536 + h*64 + ng*8);
        const ushort_t* vp = (const ushort_t*)&u;
        #pragma unroll
        for (int e = 0; e < 8; ++e) VT[(ng*8 + e)*72 + k] = vp[e];
    }
    __syncthreads();

    floatx4 accs[4] = {};
    const ushort_t* qbase = qkv + (size_t)(w*49 + wid*16 + fr)*QKV3 + h*64;
    #pragma unroll
    for (int k0 = 0; k0 < 64; k0 += 32){
        short8 af = *(const short8*)(qbase + k0 + co);
        #pragma unroll
        for (int j = 0; j < 4; ++j){
            const ushort_t* kbase = qkv + (size_t)(w*49 + j*16 + fr)*QKV3 + 768 + h*64;
            short8 bf = *(const short8*)(kbase + k0 + co);
            accs[j] = __builtin_amdgcn_mfma_f32_16x16x32_bf16(af, bf, accs[j], 0, 0, 0);
        }
    }

    const float* bmh = bm + (size_t)((h*4 + wi)*64 + wid*16)*64;
    #pragma unroll
    for (int r = 0; r < 4; ++r){
        int lrow = quad*4 + r;
        float m = -3e38f;
        #pragma unroll
        for (int j = 0; j < 4; ++j){
            float a = accs[j][r]*0.125f + bmh[lrow*64 + j*16 + fr];
            accs[j][r] = a;
            m = fmaxf(m, a);
        }
        #pragma unroll
        for (int off = 1; off < 16; off <<= 1) m = fmaxf(m, __shfl_xor(m, off, 64));
        float s = 0.f;
        #pragma unroll
        for (int j = 0; j < 4; ++j){
            float e = __expf(accs[j][r] - m);
            accs[j][r] = e; s += e;
        }
        #pragma unroll
        for (int off = 1; off < 16; off <<= 1) s += __shfl_xor(s, off, 64);
        float inv = 1.f / s;
        #pragma unroll
        for (int j = 0; j < 4; ++j)
            Ps[(wid*16 + lrow)*72 + j*16 + fr] = f2b(accs[j][r]*inv);
    }
    __syncthreads();

    floatx4 acco[4] = {};
    #pragma unroll
    for (int k0 = 0; k0 < 64; k0 += 32){
        short8 af = *(const short8*)(Ps + (wid*16 + fr)*72 + k0 + co);
        #pragma unroll
        for (int j = 0; j < 4; ++j){
            short8 bf = *(const short8*)(VT + (j*16 + fr)*72 + k0 + co);
            acco[j] = __builtin_amdgcn_mfma_f32_16x16x32_bf16(af, bf, acco[j], 0, 0, 0);
        }
    }
    // stage O tile into Ps (dead after PV), then coalesced 16B stores
    __syncthreads();
    #pragma unroll
    for (int r = 0; r < 4; ++r){
        int orow = wid*16 + quad*4 + r;
        #pragma unroll
        for (int j = 0; j < 4; ++j)
            Ps[orow*72 + j*16 + fr] = f2b(acco[j][r]);
    }
    __syncthreads();
    for (int it = tid; it < 49*8; it += 256){
        int row = it >> 3, u4c = it & 7;
        *(uint4*)(outp + (size_t)(w*49 + row)*CDIM + h*64 + u4c*8) =
            *(const uint4*)(Ps + row*72 + u4c*8);
    }
}

// ---------- depthwise 3x3 + bn1(folded)+hswish + FUSED bn2-stats ----------
__global__ __launch_bounds__(256) void dwconv_s(const ushort_t* __restrict__ in,
                                                const float* __restrict__ wT,
                                                const float* __restrict__ sums1,
                                                const float* __restrict__ g1,
                                                const float* __restrict__ b1,
                                                ushort_t* __restrict__ out,
                                                float* __restrict__ sums2){
    const int cgl = threadIdx.x & 31;
    const int rp  = threadIdx.x >> 5;
    const int cg  = blockIdx.x*32 + cgl;       // [0,384)
    const int c   = cg*8;
    const int r0  = blockIdx.y*112;
    float sc[8], sh[8];
    #pragma unroll
    for (int e = 0; e < 8; ++e) bn_coef(sums1, HID, g1, b1, c+e, sc[e], sh[e]);
    float wv[9][8];
    #pragma unroll
    for (int kk = 0; kk < 9; ++kk){
        const float4* wp = (const float4*)(wT + kk*HID + c);
        float4 w0 = wp[0], w1 = wp[1];
        wv[kk][0]=w0.x; wv[kk][1]=w0.y; wv[kk][2]=w0.z; wv[kk][3]=w0.w;
        wv[kk][4]=w1.x; wv[kk][5]=w1.y; wv[kk][6]=w1.z; wv[kk][7]=w1.w;
    }
    float s[8] = {}, q[8] = {};
    for (int r = r0 + rp; r < r0 + 112; r += 8){
        int b = r / 196, p = r % 196;
        int y = p / 14,  x = p % 14;
        const uint4* inb = (const uint4*)(in + (size_t)b*196*HID);
        float acc[8] = {};
        #pragma unroll
        for (int ky = 0; ky < 3; ++ky){
            int yy = y + ky - 1;
            if ((unsigned)yy >= 14u) continue;
            #pragma unroll
            for (int kx = 0; kx < 3; ++kx){
                int xx = x + kx - 1;
                if ((unsigned)xx >= 14u) continue;
                uint4 u = inb[(yy*14 + xx)*384 + cg];
                float fin[8]; unpack8(u, fin);
                #pragma unroll
                for (int e = 0; e < 8; ++e)
                    acc[e] += hswish(fin[e]*sc[e] + sh[e]) * wv[ky*3 + kx][e];
            }
        }
        ((uint4*)out)[(size_t)r*384 + cg] = pack8(acc);
        #pragma unroll
        for (int e = 0; e < 8; ++e){ s[e] += acc[e]; q[e] += acc[e]*acc[e]; }
    }
    #pragma unroll
    for (int e = 0; e < 8; ++e){
        s[e] += __shfl_xor(s[e], 32, 64);
        q[e] += __shfl_xor(q[e], 32, 64);
    }
    __shared__ float red[4][32][17];
    const int wvv = threadIdx.x >> 6;
    if ((threadIdx.x & 32) == 0){
        #pragma unroll
        for (int e = 0; e < 8; ++e){
            red[wvv][cgl][e]   = s[e];
            red[wvv][cgl][8+e] = q[e];
        }
    }
    __syncthreads();
    #pragma unroll
    for (int k = 0; k < 2; ++k){
        int o = threadIdx.x*2 + k;
        int cgo = o >> 4, e = o & 15;
        float v = red[0][cgo][e] + red[1][cgo][e] + red[2][cgo][e] + red[3][cgo][e];
        int cc = blockIdx.x*256 + cgo*8 + (e & 7);
        atomicAdd(&sums2[(e < 8 ? 0 : HID) + cc], v);
    }
}

// ---------- SE (bn2 folded on read) ----------
__global__ __launch_bounds__(256) void se_mean_v(const ushort_t* __restrict__ X,
                                                 const float* __restrict__ sums2,
                                                 const float* __restrict__ g2,
                                                 const float* __restrict__ b2,
                                                 float* __restrict__ s){
    const int b   = blockIdx.x;
    const int cgl = threadIdx.x & 31;
    const int rp  = threadIdx.x >> 5;
    const int cg  = blockIdx.y*32 + cgl;
    const int c   = cg*8;
    float sc[8], sh[8];
    #pragma unroll
    for (int e = 0; e < 8; ++e) bn_coef(sums2, HID, g2, b2, c+e, sc[e], sh[e]);
    const uint4* Xb = (const uint4*)(X + (size_t)b*196*HID);
    float a[8] = {};
    for (int p = rp; p < 196; p += 8){
        uint4 u = Xb[(size_t)p*384 + cg];
        float f[8]; unpack8(u, f);
        #pragma unroll
        for (int e = 0; e < 8; ++e) a[e] += hswish(f[e]*sc[e] + sh[e]);
    }
    #pragma unroll
    for (int e = 0; e < 8; ++e) a[e] += __shfl_xor(a[e], 32, 64);
    __shared__ float red[4][32][9];
    const int wv = threadIdx.x >> 6;
    if ((threadIdx.x & 32) == 0){
        #pragma unroll
        for (int e = 0; e < 8; ++e) red[wv][cgl][e] = a[e];
    }
    __syncthreads();
    {
        int o = threadIdx.x;
        int cgo = o >> 3, e = o & 7;
        float v = red[0][cgo][e] + red[1][cgo][e] + red[2][cgo][e] + red[3][cgo][e];
        s[(size_t)b*HID + blockIdx.y*256 + cgo*8 + e] = v * (1.f/196.f);
    }
}
__global__ __launch_bounds__(256) void se_fc(const float* __restrict__ in,
                                             const float* __restrict__ w,
                                             const float* __restrict__ bias,
                                             float* __restrict__ out,
                                             int IN, int OUT, int mode){
    int wv   = (blockIdx.x*256 + threadIdx.x) >> 6;
    int lane = threadIdx.x & 63;
    if (wv >= OUT) return;
    const float* wr = w + (size_t)wv * IN;
    float acc[32];
    #pragma unroll
    for (int b = 0; b < 32; ++b) acc[b] = 0.f;
    for (int k = lane; k < IN; k += 64){
        float wval = wr[k];
        #pragma unroll
        for (int b = 0; b < 32; ++b)
            acc[b] += in[b*IN + k] * wval;
    }
    #pragma unroll
    for (int b = 0; b < 32; ++b){
        float v = acc[b];
        #pragma unroll
        for (int off = 32; off; off >>= 1) v += __shfl_down(v, off, 64);
        if (lane == 0){
            float a = v + bias[wv];
            if (mode == 0) a = fmaxf(a, 0.f);
            else           a = fminf(fmaxf(a + 3.f, 0.f), 6.f) * (1.f/6.f);
            out[b*OUT + wv] = a;
        }
    }
}
__global__ __launch_bounds__(256) void se_scale(ushort_t* __restrict__ X,
                                                const float* __restrict__ sums2,
                                                const float* __restrict__ g2,
                                                const float* __restrict__ b2,
                                                const float* __restrict__ s2){
    int idx = blockIdx.x*256 + threadIdx.x;
    if (idx >= MROWS * (HID/8)) return;
    int r = idx / (HID/8), c8 = idx % (HID/8);
    int b = r / 196;
    int c = c8*8;
    uint4 u = ((uint4*)X)[idx];
    float f[8]; unpack8(u, f);
    const float* sp = s2 + b*HID + c;
    #pragma unroll
    for (int e = 0; e < 8; ++e){
        float sc, sh;
        bn_coef(sums2, HID, g2, b2, c+e, sc, sh);
        f[e] = hswish(f[e]*sc + sh) * sp[e];
    }
    ((uint4*)X)[idx] = pack8(f);
}

// ---------- final: out = [cls | f_bf16 + h_bf16*sc + sh], bn3 folded ----------
__global__ __launch_bounds__(256) void final_k(const float4* __restrict__ xin,
                                               const ushort_t* __restrict__ fb,
                                               const ushort_t* __restrict__ hb4,
                                               const float* __restrict__ sums3,
                                               const float* __restrict__ g3,
                                               const float* __restrict__ b3,
                                               float4* __restrict__ outp){
    int idx = blockIdx.x*256 + threadIdx.x;        // over 32*197*96 (8-elem groups)
    if (idx >= 32*197*96) return;
    int b = idx / (197*96);
    int rem = idx % (197*96);
    int n = rem / 96, c8 = rem % 96;
    size_t obase = ((size_t)b*197 + n)*192 + c8*2;
    if (n == 0){
        outp[obase]     = xin[obase];
        outp[obase + 1] = xin[obase + 1];
        return;
    }
    size_t off = ((size_t)b*196 + n - 1)*96 + c8;
    uint4 fu = ((const uint4*)fb)[off];
    uint4 hu = ((const uint4*)hb4)[off];
    float fv[8], hv[8];
    unpack8(fu, fv); unpack8(hu, hv);
    int c = c8*8;
    float o[8];
    #pragma unroll
    for (int e = 0; e < 8; ++e){
        float sc, sh;
        bn_coef(sums3, CDIM, g3, b3, c+e, sc, sh);
        o[e] = fv[e] + hv[e]*sc + sh;
    }
    float4 o0 = {o[0], o[1], o[2], o[3]};
    float4 o1 = {o[4], o[5], o[6], o[7]};
    outp[obase]     = o0;
    outp[obase + 1] = o1;
}

extern "C" void kernel_launch(void* const* d_in, const int* in_sizes, int n_in,
                              void* d_out, int out_size, void* d_ws, size_t ws_size,
                              hipStream_t stream){
    const float* x      = (const float*)d_in[0];
    const float* w_qkv  = (const float*)d_in[1];
    const float* w_proj = (const float*)d_in[2];
    const float* b_proj = (const float*)d_in[3];
    const float* rpb    = (const float*)d_in[4];
    const float* pw1_w  = (const float*)d_in[5];
    const float* bn1_g  = (const float*)d_in[6];
    const float* bn1_b  = (const float*)d_in[7];
    const float* dw_w   = (const float*)d_in[8];
    const float* bn2_g  = (const float*)d_in[9];
    const float* bn2_b  = (const float*)d_in[10];
    const float* se_w1  = (const float*)d_in[11];
    const float* se_b1  = (const float*)d_in[12];
    const float* se_w2  = (const float*)d_in[13];
    const float* se_b2  = (const float*)d_in[14];
    const float* pw2_w  = (const float*)d_in[15];
    const float* bn3_g  = (const float*)d_in[16];
    const float* bn3_b  = (const float*)d_in[17];

    char* ws = (char*)d_ws;
    // Lifetime map (as r11/r12; unchanged):
    //  [0, 9.63M):        win (prep) -> dead after qkv gemm -> hb (dwconv out)
    //  [9.63M, 38.54M):   qkv (qkv gemm -> attn)
    //  [38.54M, 48.17M):  wqkvb (prep) -> attnb (attn out) -> ha (pw1 out) -> hb4 (pw2 out)
    //  [48.17M, 49.35M):  wprojb (prep -> proj)
    //  [49.35M, 50.13M):  bm (prep -> attn; clobbered later by ha)
    //  [50.13M, 77.07M):  ha tail (pw1 out spans [38.54M, 77.07M))
    //  [77.07M, 86.70M):  fb2 (proj out; lives to final_k)
    //  [86.70M, 86.73M):  sums2 | sums3 (contiguous, zeroed in prep)
    //  [86.73M, 91.45M):  pw1b (prep -> pw1 gemm; untouched in between)
    //  [91.45M, 96.17M):  pw2b (prep -> pw2 gemm; untouched in between)
    //  [96.34M, ...):     sums1 | s | s1 | s2/dwwT
    ushort_t* win    = (ushort_t*)(ws + 0);
    ushort_t* hb     = (ushort_t*)(ws + 0);
    ushort_t* qkv    = (ushort_t*)(ws + 9633792);
    ushort_t* wqkvb  = (ushort_t*)(ws + 38535168);
    ushort_t* attnb  = (ushort_t*)(ws + 38535168);
    ushort_t* ha     = (ushort_t*)(ws + 38535168);
    ushort_t* hb4    = (ushort_t*)(ws + 38535168);
    ushort_t* wprojb = (ushort_t*)(ws + 48168960);
    float*    bm     = (float*)(ws + 49348608);
    ushort_t* fb2    = (ushort_t*)(ws + 77070336);
    float*    sums2  = (float*)(ws + 86704128);
    float*    sums3  = (float*)(ws + 86728704);
    ushort_t* pw1b   = (ushort_t*)(ws + 86734848);
    ushort_t* pw2b   = (ushort_t*)(ws + 91453440);
    float*    sums1  = (float*)(ws + 96337920);
    float*    s      = (float*)(ws + 96362496);
    float*    s1     = (float*)(ws + 96755712);
    float*    s2     = (float*)(ws + 96854016);
    float*    dwwT   = (float*)(ws + 96854016);    // alias s2: dead before se_fc writes s2

    const int vec_hid8 = (MROWS*(HID/8) + 255)/256;
    const int GY = 56;
    const int GY256 = 32;   // 25 row-tiles of 256 padded to multiple of 8

    // single fused prep: zeros + dwT + 4 weight casts + window gather + bias/mask table
    prep_k<<<12546, 256, 0, stream>>>((const float4*)x, (const float4*)w_qkv,
                                      (const float4*)w_proj, (const float4*)pw1_w,
                                      (const float4*)pw2_w, dw_w, rpb,
                                      sums1, sums2, dwwT,
                                      (ushort4*)wqkvb, (ushort4*)wprojb,
                                      (ushort4*)pw1b, (ushort4*)pw2b,
                                      (ushort4*)win, bm);

    // attention half
    gemm256_32<<<dim3(QKV3/128, GY256), 512, 0, stream>>>(win, wqkvb, qkv, MROWS, QKV3, CDIM, nullptr);
    attn_mfma<<<dim3(12, 128), 256, 0, stream>>>(qkv, attnb, bm);
    gemm_bt64<<<dim3(CDIM/64, GY), 256, 0, stream>>>(attnb, wprojb, fb2, nullptr, MROWS, CDIM, CDIM, b_proj, nullptr, 1);

    // ConvFFN half
    gemm256_32<<<dim3(HID/128, GY256), 512, 0, stream>>>(fb2, pw1b, ha, MROWS, HID, CDIM, sums1);
    dwconv_s<<<dim3(12, GY), 256, 0, stream>>>(ha, dwwT, sums1, bn1_g, bn1_b, hb, sums2);   // bn1 folded + bn2-stats
    se_mean_v<<<dim3(32, 12), 256, 0, stream>>>(hb, sums2, bn2_g, bn2_b, s);                // bn2 folded
    se_fc<<<dim3((CDIM*64)/256), 256, 0, stream>>>(s, se_w1, se_b1, s1, HID, CDIM, 0);
    se_fc<<<dim3((HID*64)/256), 256, 0, stream>>>(s1, se_w2, se_b2, s2, CDIM, HID, 1);
    se_scale<<<vec_hid8, 256, 0, stream>>>(hb, sums2, bn2_g, bn2_b, s2);                    // bn2 folded

    gemm_bt64<<<dim3(CDIM/64, GY), 256, 0, stream>>>(hb, pw2b, hb4, nullptr, MROWS, CDIM, HID, nullptr, sums3, 0);
    final_k<<<(32*197*96 + 255)/256, 256, 0, stream>>>((const float4*)x, fb2, hb4, sums3, bn3_g, bn3_b, (float4*)d_out);
}